// Round 6
// baseline (877.253 us; speedup 1.0000x reference)
//
#include <hip/hip_runtime.h>
#include <hip/hip_bf16.h>

#define EMB 512
#define NHEADS 8
#define HD 64
#define SEQ 2048

typedef float f32x4 __attribute__((ext_vector_type(4)));
typedef short short8 __attribute__((ext_vector_type(8)));
typedef unsigned short ushort4_t __attribute__((ext_vector_type(4)));

#define MFMA(a, b, c) __builtin_amdgcn_mfma_f32_16x16x32_bf16((a), (b), (c), 0, 0, 0)

__device__ inline unsigned short f2bf(float f) {
    union { float f; unsigned u; } v; v.f = f;
    unsigned r = v.u + 0x7fffu + ((v.u >> 16) & 1u);   // round-to-nearest-even
    return (unsigned short)(r >> 16);
}

__device__ inline unsigned cvt_pk_bf16(float a, float b) {
    unsigned r;
    asm("v_cvt_pk_bf16_f32 %0, %1, %2" : "=v"(r) : "v"(a), "v"(b));
    return r;  // low16 = bf16(a), high16 = bf16(b)
}

// compiler-opaque register barrier: prevents LICM/DCE on ablation variants
__device__ inline void opaque(short8 &x) { asm volatile("" : "+v"(x)); }

__device__ inline short8 f8_to_bf8(float4 a, float4 b) {
    short8 r;
    r[0] = (short)f2bf(a.x); r[1] = (short)f2bf(a.y);
    r[2] = (short)f2bf(a.z); r[3] = (short)f2bf(a.w);
    r[4] = (short)f2bf(b.x); r[5] = (short)f2bf(b.y);
    r[6] = (short)f2bf(b.z); r[7] = (short)f2bf(b.w);
    return r;
}

// ---------------------------------------------------------------------------
// Kernel 1: per-head QKV projection (unchanged from round 5)
// ---------------------------------------------------------------------------
__global__ __launch_bounds__(256) void qkv_proj_kernel(
    const float* __restrict__ vin, const float* __restrict__ kin,
    const float* __restrict__ qin,
    const float* __restrict__ Wv, const float* __restrict__ Wk,
    const float* __restrict__ Wq,
    unsigned short* __restrict__ q_ws, unsigned short* __restrict__ k_ws,
    unsigned short* __restrict__ vt_ws)
{
    const int z = blockIdx.y;
    const float* __restrict__ x = (z == 0) ? qin : (z == 1 ? kin : vin);
    const float* __restrict__ W = (z == 0) ? Wq : (z == 1 ? Wk : Wv);

    const int bid = blockIdx.x;
    const int st = bid & 31;
    const int h  = (bid >> 5) & 7;
    const int n  = bid >> 8;

    const int lane = threadIdx.x & 63;
    const int w    = threadIdx.x >> 6;
    const int lo = lane & 15, hi = lane >> 4;
    const int s_base = st * 64 + w * 16;

    const float* xr = x + ((size_t)n * SEQ + s_base + lo) * EMB + h * HD;
    short8 a[2];
#pragma unroll
    for (int kb = 0; kb < 2; ++kb) {
        const float4* p = (const float4*)(xr + kb * 32 + hi * 8);
        a[kb] = f8_to_bf8(p[0], p[1]);
    }
    short8 b[2][4];
#pragma unroll
    for (int nb = 0; nb < 4; ++nb) {
        const float* wr = W + (lo + 16 * nb) * HD;
#pragma unroll
        for (int kb = 0; kb < 2; ++kb) {
            const float4* p = (const float4*)(wr + kb * 32 + hi * 8);
            b[kb][nb] = f8_to_bf8(p[0], p[1]);
        }
    }
    f32x4 acc[4];
#pragma unroll
    for (int nb = 0; nb < 4; ++nb) {
        f32x4 t = {0.f, 0.f, 0.f, 0.f};
        t = MFMA(a[0], b[0][nb], t);
        t = MFMA(a[1], b[1][nb], t);
        acc[nb] = t;
    }
    const size_t nh = (size_t)n * NHEADS + h;
    if (z < 2) {
        const float sc = (z == 0) ? 0.18033688011112042f : 1.0f; // log2(e)/8
        unsigned short* o = (z == 0 ? q_ws : k_ws) + nh * SEQ * HD;
#pragma unroll
        for (int nb = 0; nb < 4; ++nb)
#pragma unroll
            for (int i = 0; i < 4; ++i)
                o[(size_t)(s_base + hi * 4 + i) * HD + lo + 16 * nb] =
                    f2bf(acc[nb][i] * sc);
    } else {
        unsigned short* o = vt_ws + nh * HD * SEQ;
#pragma unroll
        for (int nb = 0; nb < 4; ++nb) {
            ushort4_t pk;
            pk[0] = f2bf(acc[nb][0]); pk[1] = f2bf(acc[nb][1]);
            pk[2] = f2bf(acc[nb][2]); pk[3] = f2bf(acc[nb][3]);
            *(ushort4_t*)(o + (size_t)(lo + 16 * nb) * SEQ + s_base + hi * 4) = pk;
        }
    }
}

// ---------------------------------------------------------------------------
// Kernel 2: Wo fp32 -> bf16 (unchanged)
// ---------------------------------------------------------------------------
__global__ __launch_bounds__(256) void wconv_kernel(
    const float* __restrict__ Wo, unsigned short* __restrict__ wob)
{
    const int idx = (blockIdx.x * 256 + threadIdx.x) * 8;
    const float4* p = (const float4*)(Wo + idx);
    short8 r = f8_to_bf8(p[0], p[1]);
    *(short8*)(wob + idx) = r;
}

// ---------------------------------------------------------------------------
// Kernel 3: ABLATION template. V0=full (launched LAST -> correct output).
//  V1: K/V loads hoisted (isolates global-load latency)
//  V2: no softmax VALU (isolates exp2/mask cost)
//  V3: no LDS round-trip (isolates LDS serialization)
//  V4: floor (all three removed)
// ---------------------------------------------------------------------------
template<int V>
__global__ __launch_bounds__(256) void attn_kernel(
    const unsigned short* __restrict__ q_ws, const unsigned short* __restrict__ k_ws,
    const unsigned short* __restrict__ vt_ws, const int* __restrict__ mask,
    unsigned short* __restrict__ ao_ws)
{
    constexpr bool HOIST_KV   = (V == 1 || V == 4);
    constexpr bool DO_SOFTMAX = (V == 0 || V == 1 || V == 3);
    constexpr bool USE_LDS    = (V == 0 || V == 1 || V == 2);

    __shared__ __align__(16) unsigned short plds[4][16][88];

    const int lane = threadIdx.x & 63;
    const int w = threadIdx.x >> 6;
    const int lo = lane & 15, hi = lane >> 4;
    const int bid = (blockIdx.x & 7) * 128 + (blockIdx.x >> 3); // XCD swizzle
    const int wid = bid * 4 + w;
    const int qt = wid & 127;
    const int h  = (wid >> 7) & 7;
    const int n  = wid >> 10;
    const size_t nh = (size_t)n * NHEADS + h;

    const unsigned short* qp = q_ws + nh * SEQ * HD;
    const unsigned short* kp = k_ws + nh * SEQ * HD;
    const unsigned short* vp = vt_ws + nh * HD * SEQ;
    const int* mp = mask + (size_t)n * SEQ;

    const int q0 = qt * 16;
    short8 aq[2];
#pragma unroll
    for (int kb = 0; kb < 2; ++kb)
        aq[kb] = *(const short8*)(qp + (size_t)(q0 + lo) * HD + kb * 32 + hi * 8);

    f32x4 o[4];
    float lacc = 0.f;
#pragma unroll
    for (int nb = 0; nb < 4; ++nb) o[nb] = (f32x4){0.f, 0.f, 0.f, 0.f};

    short8 hk0[4], hk1[4], hv0[4], hv1[4];
    if constexpr (HOIST_KV) {
#pragma unroll
        for (int nb = 0; nb < 4; ++nb) {
            const unsigned short* kr = kp + (size_t)(16 * nb + lo) * HD + hi * 8;
            hk0[nb] = *(const short8*)kr;
            hk1[nb] = *(const short8*)(kr + 32);
            const unsigned short* vr = vp + (size_t)(16 * nb + lo) * SEQ + hi * 8;
            hv0[nb] = *(const short8*)vr;
            hv1[nb] = *(const short8*)(vr + 32);
        }
    }

    for (int kt = 0; kt < SEQ; kt += 64) {
        short8 k0[4], k1[4], va0[4], va1[4];
        if constexpr (HOIST_KV) {
#pragma unroll
            for (int nb = 0; nb < 4; ++nb) {
                k0[nb] = hk0[nb]; k1[nb] = hk1[nb];
                va0[nb] = hv0[nb]; va1[nb] = hv1[nb];
                opaque(k0[nb]); opaque(k1[nb]);   // defeat LICM of MFMAs
                opaque(va0[nb]); opaque(va1[nb]);
            }
        } else {
#pragma unroll
            for (int nb = 0; nb < 4; ++nb) {
                const unsigned short* vr = vp + (size_t)(16 * nb + lo) * SEQ + kt + hi * 8;
                va0[nb] = *(const short8*)vr;
                va1[nb] = *(const short8*)(vr + 32);
                const unsigned short* kr = kp + (size_t)(kt + 16 * nb + lo) * HD + hi * 8;
                k0[nb] = *(const short8*)kr;
                k1[nb] = *(const short8*)(kr + 32);
            }
        }
        // S^T = K Q^T : D[key][q]; lane holds keys 16nb+4hi+i for q = lo
        f32x4 e[4];
#pragma unroll
        for (int nb = 0; nb < 4; ++nb) {
            f32x4 t = {0.f, 0.f, 0.f, 0.f};
            t = MFMA(k0[nb], aq[0], t);
            t = MFMA(k1[nb], aq[1], t);
            e[nb] = t;
        }
        uint2 pk[4];
        if constexpr (DO_SOFTMAX) {
#pragma unroll
            for (int nb = 0; nb < 4; ++nb) {
                const int4 mm = *(const int4*)(mp + kt + 16 * nb + 4 * hi);
                float p0 = __builtin_amdgcn_exp2f(mm.x == 0 ? -1e30f : e[nb][0]);
                float p1 = __builtin_amdgcn_exp2f(mm.y == 0 ? -1e30f : e[nb][1]);
                float p2 = __builtin_amdgcn_exp2f(mm.z == 0 ? -1e30f : e[nb][2]);
                float p3 = __builtin_amdgcn_exp2f(mm.w == 0 ? -1e30f : e[nb][3]);
                lacc += (p0 + p1) + (p2 + p3);
                pk[nb].x = cvt_pk_bf16(p0, p1);
                pk[nb].y = cvt_pk_bf16(p2, p3);
            }
        } else {
#pragma unroll
            for (int nb = 0; nb < 4; ++nb) {
                lacc += (e[nb][0] + e[nb][1]) + (e[nb][2] + e[nb][3]);
                pk[nb].x = cvt_pk_bf16(e[nb][0], e[nb][1]);
                pk[nb].y = cvt_pk_bf16(e[nb][2], e[nb][3]);
            }
        }
        short8 pa0, pa1;
        if constexpr (USE_LDS) {
#pragma unroll
            for (int nb = 0; nb < 4; ++nb)
                *(uint2*)(&plds[w][lo][16 * nb + 4 * hi]) = pk[nb];
            pa0 = *(const short8*)(&plds[w][lo][hi * 8]);
            pa1 = *(const short8*)(&plds[w][lo][32 + hi * 8]);
        } else {
            union { uint2 u[2]; short8 s; } c0, c1;
            c0.u[0] = pk[0]; c0.u[1] = pk[1];
            c1.u[0] = pk[2]; c1.u[1] = pk[3];
            pa0 = c0.s; pa1 = c1.s;
        }
        // O^T += V^T P^T
#pragma unroll
        for (int nb = 0; nb < 4; ++nb) {
            o[nb] = MFMA(va0[nb], pa0, o[nb]);
            o[nb] = MFMA(va1[nb], pa1, o[nb]);
        }
    }
    lacc += __shfl_xor(lacc, 16);
    lacc += __shfl_xor(lacc, 32);
    const float linv = 1.0f / lacc;

    unsigned short* op = ao_ws + ((size_t)n * SEQ + q0 + lo) * EMB + h * HD;
#pragma unroll
    for (int nb = 0; nb < 4; ++nb) {
        ushort4_t pkk;
        pkk[0] = f2bf(o[nb][0] * linv);
        pkk[1] = f2bf(o[nb][1] * linv);
        pkk[2] = f2bf(o[nb][2] * linv);
        pkk[3] = f2bf(o[nb][3] * linv);
        *(ushort4_t*)(op + 16 * nb + 4 * hi) = pkk;
    }
}

// ---------------------------------------------------------------------------
// Kernel 4: output projection (unchanged)
// ---------------------------------------------------------------------------
__global__ __launch_bounds__(256) void out_proj_kernel(
    const unsigned short* __restrict__ ao_ws, const unsigned short* __restrict__ wob,
    const float* __restrict__ bo, float* __restrict__ out)
{
    const int bid = blockIdx.x;
    const int nc = bid & 7;
    const int mt = bid >> 3;
    const int lane = threadIdx.x & 63;
    const int w = threadIdx.x >> 6;
    const int lo = lane & 15, hi = lane >> 4;
    const int m0 = mt * 64 + w * 16;
    const int e0 = nc * 64;

    f32x4 acc[4];
#pragma unroll
    for (int nb = 0; nb < 4; ++nb) acc[nb] = (f32x4){0.f, 0.f, 0.f, 0.f};

    const unsigned short* ar = ao_ws + (size_t)(m0 + lo) * EMB;
    for (int k0 = 0; k0 < EMB; k0 += 32) {
        short8 a = *(const short8*)(ar + k0 + hi * 8);
#pragma unroll
        for (int nb = 0; nb < 4; ++nb) {
            short8 b = *(const short8*)(wob + (size_t)(e0 + lo + 16 * nb) * EMB + k0 + hi * 8);
            acc[nb] = MFMA(a, b, acc[nb]);
        }
    }
#pragma unroll
    for (int nb = 0; nb < 4; ++nb) {
        float bias = bo[e0 + lo + 16 * nb];
#pragma unroll
        for (int i = 0; i < 4; ++i)
            out[(size_t)(m0 + hi * 4 + i) * EMB + e0 + lo + 16 * nb] = acc[nb][i] + bias;
    }
}

// ---------------------------------------------------------------------------
extern "C" void kernel_launch(void* const* d_in, const int* in_sizes, int n_in,
                              void* d_out, int out_size, void* d_ws, size_t ws_size,
                              hipStream_t stream)
{
    const float* vin = (const float*)d_in[0];
    const float* kin = (const float*)d_in[1];
    const float* qin = (const float*)d_in[2];
    const int*  mask = (const int*)d_in[3];
    const float* Wv  = (const float*)d_in[4];
    const float* Wk  = (const float*)d_in[5];
    const float* Wq  = (const float*)d_in[6];
    const float* Wo  = (const float*)d_in[7];
    const float* bo  = (const float*)d_in[8];
    float* out = (float*)d_out;

    const int N = in_sizes[0] / (SEQ * EMB);   // 4

    char* ws = (char*)d_ws;
    const size_t qkv_bytes = (size_t)N * NHEADS * SEQ * HD * 2;  // 8.39 MB each
    unsigned short* q_ws  = (unsigned short*)(ws);
    unsigned short* k_ws  = (unsigned short*)(ws + qkv_bytes);
    unsigned short* vt_ws = (unsigned short*)(ws + 2 * qkv_bytes);
    unsigned short* ao_ws = (unsigned short*)(ws + 3 * qkv_bytes);
    unsigned short* wob   = (unsigned short*)(ws + 4 * qkv_bytes);

    const dim3 agrid(N * NHEADS * (SEQ / 16) / 4);

    hipLaunchKernelGGL(wconv_kernel, dim3(EMB * EMB / 2048), dim3(256), 0, stream,
                       Wo, wob);
    hipLaunchKernelGGL(qkv_proj_kernel, dim3(N * NHEADS * (SEQ / 64), 3), dim3(256), 0, stream,
                       vin, kin, qin, Wv, Wk, Wq, q_ws, k_ws, vt_ws);
    // ablation dispatches (results overwritten by the final full variant)
    hipLaunchKernelGGL((attn_kernel<1>), agrid, dim3(256), 0, stream,
                       q_ws, k_ws, vt_ws, mask, ao_ws);
    hipLaunchKernelGGL((attn_kernel<2>), agrid, dim3(256), 0, stream,
                       q_ws, k_ws, vt_ws, mask, ao_ws);
    hipLaunchKernelGGL((attn_kernel<3>), agrid, dim3(256), 0, stream,
                       q_ws, k_ws, vt_ws, mask, ao_ws);
    hipLaunchKernelGGL((attn_kernel<4>), agrid, dim3(256), 0, stream,
                       q_ws, k_ws, vt_ws, mask, ao_ws);
    // full variant LAST: ao_ws left correct for out_proj
    hipLaunchKernelGGL((attn_kernel<0>), agrid, dim3(256), 0, stream,
                       q_ws, k_ws, vt_ws, mask, ao_ws);
    hipLaunchKernelGGL(out_proj_kernel, dim3((N * SEQ / 64) * (EMB / 64)), dim3(256), 0, stream,
                       ao_ws, wob, bo, out);
}

// Round 9
// 199.696 us; speedup vs baseline: 4.3929x; 4.3929x over previous
//
#include <hip/hip_runtime.h>
#include <hip/hip_bf16.h>

#define EMB 512
#define NHEADS 8
#define HD 64
#define SEQ 2048

typedef float f32x4 __attribute__((ext_vector_type(4)));
typedef short short8 __attribute__((ext_vector_type(8)));
typedef unsigned short ushort4_t __attribute__((ext_vector_type(4)));

#define MFMA(a, b, c) __builtin_amdgcn_mfma_f32_16x16x32_bf16((a), (b), (c), 0, 0, 0)

__device__ inline unsigned short f2bf(float f) {
    union { float f; unsigned u; } v; v.f = f;
    unsigned r = v.u + 0x7fffu + ((v.u >> 16) & 1u);   // round-to-nearest-even
    return (unsigned short)(r >> 16);
}

__device__ inline unsigned cvt_pk_bf16(float a, float b) {
    unsigned r;
    asm("v_cvt_pk_bf16_f32 %0, %1, %2" : "=v"(r) : "v"(a), "v"(b));
    return r;  // low16 = bf16(a), high16 = bf16(b)
}

__device__ inline short8 f8_to_bf8(float4 a, float4 b) {
    short8 r;
    r[0] = (short)f2bf(a.x); r[1] = (short)f2bf(a.y);
    r[2] = (short)f2bf(a.z); r[3] = (short)f2bf(a.w);
    r[4] = (short)f2bf(b.x); r[5] = (short)f2bf(b.y);
    r[6] = (short)f2bf(b.z); r[7] = (short)f2bf(b.w);
    return r;
}

// ---------------------------------------------------------------------------
// Kernel 1: per-head QKV projection (unchanged, known-good)
// ---------------------------------------------------------------------------
__global__ __launch_bounds__(256) void qkv_proj_kernel(
    const float* __restrict__ vin, const float* __restrict__ kin,
    const float* __restrict__ qin,
    const float* __restrict__ Wv, const float* __restrict__ Wk,
    const float* __restrict__ Wq,
    unsigned short* __restrict__ q_ws, unsigned short* __restrict__ k_ws,
    unsigned short* __restrict__ vt_ws)
{
    const int z = blockIdx.y;
    const float* __restrict__ x = (z == 0) ? qin : (z == 1 ? kin : vin);
    const float* __restrict__ W = (z == 0) ? Wq : (z == 1 ? Wk : Wv);

    const int bid = blockIdx.x;
    const int st = bid & 31;
    const int h  = (bid >> 5) & 7;
    const int n  = bid >> 8;

    const int lane = threadIdx.x & 63;
    const int w    = threadIdx.x >> 6;
    const int lo = lane & 15, hi = lane >> 4;
    const int s_base = st * 64 + w * 16;

    const float* xr = x + ((size_t)n * SEQ + s_base + lo) * EMB + h * HD;
    short8 a[2];
#pragma unroll
    for (int kb = 0; kb < 2; ++kb) {
        const float4* p = (const float4*)(xr + kb * 32 + hi * 8);
        a[kb] = f8_to_bf8(p[0], p[1]);
    }
    short8 b[2][4];
#pragma unroll
    for (int nb = 0; nb < 4; ++nb) {
        const float* wr = W + (lo + 16 * nb) * HD;
#pragma unroll
        for (int kb = 0; kb < 2; ++kb) {
            const float4* p = (const float4*)(wr + kb * 32 + hi * 8);
            b[kb][nb] = f8_to_bf8(p[0], p[1]);
        }
    }
    f32x4 acc[4];
#pragma unroll
    for (int nb = 0; nb < 4; ++nb) {
        f32x4 t = {0.f, 0.f, 0.f, 0.f};
        t = MFMA(a[0], b[0][nb], t);
        t = MFMA(a[1], b[1][nb], t);
        acc[nb] = t;
    }
    const size_t nh = (size_t)n * NHEADS + h;
    if (z < 2) {
        const float sc = (z == 0) ? 0.18033688011112042f : 1.0f; // log2(e)/8
        unsigned short* o = (z == 0 ? q_ws : k_ws) + nh * SEQ * HD;
#pragma unroll
        for (int nb = 0; nb < 4; ++nb)
#pragma unroll
            for (int i = 0; i < 4; ++i)
                o[(size_t)(s_base + hi * 4 + i) * HD + lo + 16 * nb] =
                    f2bf(acc[nb][i] * sc);
    } else {
        unsigned short* o = vt_ws + nh * HD * SEQ;
#pragma unroll
        for (int nb = 0; nb < 4; ++nb) {
            ushort4_t pk;
            pk[0] = f2bf(acc[nb][0]); pk[1] = f2bf(acc[nb][1]);
            pk[2] = f2bf(acc[nb][2]); pk[3] = f2bf(acc[nb][3]);
            *(ushort4_t*)(o + (size_t)(lo + 16 * nb) * SEQ + s_base + hi * 4) = pk;
        }
    }
}

// ---------------------------------------------------------------------------
// Kernel 2: Wo fp32 -> bf16 (unchanged)
// ---------------------------------------------------------------------------
__global__ __launch_bounds__(256) void wconv_kernel(
    const float* __restrict__ Wo, unsigned short* __restrict__ wob)
{
    const int idx = (blockIdx.x * 256 + threadIdx.x) * 8;
    const float4* p = (const float4*)(Wo + idx);
    short8 r = f8_to_bf8(p[0], p[1]);
    *(short8*)(wob + idx) = r;
}

// ---------------------------------------------------------------------------
// Kernel 2b: per-(n, 64-key-tile) mask-zero flags. flags[n] bit t = 1 iff
// mask[n][64t..64t+63] contains a zero. (All-ones mask -> flags = 0.)
// ---------------------------------------------------------------------------
__global__ __launch_bounds__(64) void maskflags_kernel(
    const int* __restrict__ mask, unsigned* __restrict__ flags)
{
    const int n = blockIdx.x;
    const int t = threadIdx.x;           // 64 threads; 0..31 scan tiles
    bool has0 = false;
    if (t < 32) {
        const int* mrow = mask + (size_t)n * SEQ + t * 64;
#pragma unroll 4
        for (int j = 0; j < 64; j += 4) {
            int4 m4 = *(const int4*)(mrow + j);
            has0 |= (m4.x == 0) | (m4.y == 0) | (m4.z == 0) | (m4.w == 0);
        }
    }
    unsigned long long b = __ballot(has0);
    if (t == 0) flags[n] = (unsigned)(b & 0xffffffffu);
}

// ---------------------------------------------------------------------------
// Kernel 3: flash attention, 2 q-tiles (32 q-rows) per wave.
// K/V tile loads are shared by both q-tiles (per-work load traffic halved,
// MFMA:load ratio doubled, two independent softmax->PV chains for ILP).
// Mask handling hoisted out of the fast path via precomputed per-tile flags
// (block-uniform branch). Swapped-operand QK^T, no-max softmax, per-wave
// LDS P-transpose — math identical to the passing round-5 kernel.
// ---------------------------------------------------------------------------
__global__ __launch_bounds__(256) void attn_kernel(
    const unsigned short* __restrict__ q_ws, const unsigned short* __restrict__ k_ws,
    const unsigned short* __restrict__ vt_ws, const int* __restrict__ mask,
    const unsigned* __restrict__ flags, unsigned short* __restrict__ ao_ws)
{
    __shared__ __align__(16) unsigned short plds[4][2][16][72];

    const int lane = threadIdx.x & 63;
    const int w = threadIdx.x >> 6;
    const int lo = lane & 15, hi = lane >> 4;
    // XCD swizzle, grid=512 (bijective): each (n,h) stream -> one XCD's L2
    const int bid = (blockIdx.x & 7) * 64 + (blockIdx.x >> 3);
    const int wid = bid * 4 + w;
    const int qt2 = wid & 63;          // 32-row q-block index (S/32 = 64)
    const int h   = (wid >> 6) & 7;
    const int n   = wid >> 9;
    const size_t nh = (size_t)n * NHEADS + h;

    const unsigned short* qp = q_ws + nh * SEQ * HD;
    const unsigned short* kp = k_ws + nh * SEQ * HD;
    const unsigned short* vp = vt_ws + nh * HD * SEQ;
    const int* mp = mask + (size_t)n * SEQ;
    const unsigned fl = flags[n];

    const int q0 = qt2 * 32;
    short8 aqA[2], aqB[2];
#pragma unroll
    for (int kb = 0; kb < 2; ++kb) {
        aqA[kb] = *(const short8*)(qp + (size_t)(q0 + lo) * HD + kb * 32 + hi * 8);
        aqB[kb] = *(const short8*)(qp + (size_t)(q0 + 16 + lo) * HD + kb * 32 + hi * 8);
    }

    f32x4 oA[4], oB[4];
    float laccA = 0.f, laccB = 0.f;
#pragma unroll
    for (int nb = 0; nb < 4; ++nb) {
        oA[nb] = (f32x4){0.f, 0.f, 0.f, 0.f};
        oB[nb] = (f32x4){0.f, 0.f, 0.f, 0.f};
    }

    for (int t = 0; t < 32; ++t) {
        const int kt = t * 64;
        // V^T fragments: issue early (consumed after softmax), shared A/B
        short8 va0[4], va1[4];
#pragma unroll
        for (int nb = 0; nb < 4; ++nb) {
            const unsigned short* vr = vp + (size_t)(16 * nb + lo) * SEQ + kt + hi * 8;
            va0[nb] = *(const short8*)vr;
            va1[nb] = *(const short8*)(vr + 32);
        }
        // S^T = K Q^T for both q-tiles; K fragments shared
        f32x4 eA[4], eB[4];
#pragma unroll
        for (int nb = 0; nb < 4; ++nb) {
            const unsigned short* kr = kp + (size_t)(kt + 16 * nb + lo) * HD + hi * 8;
            short8 k0 = *(const short8*)kr;
            short8 k1 = *(const short8*)(kr + 32);
            f32x4 ta = {0.f, 0.f, 0.f, 0.f};
            ta = MFMA(k0, aqA[0], ta);
            ta = MFMA(k1, aqA[1], ta);
            eA[nb] = ta;
            f32x4 tb = {0.f, 0.f, 0.f, 0.f};
            tb = MFMA(k0, aqB[0], tb);
            tb = MFMA(k1, aqB[1], tb);
            eB[nb] = tb;
        }
        // masked tiles only: fold mask into scores (block-uniform branch)
        if (fl & (1u << t)) {
#pragma unroll
            for (int nb = 0; nb < 4; ++nb) {
                const int4 mm = *(const int4*)(mp + kt + 16 * nb + 4 * hi);
                if (mm.x == 0) { eA[nb][0] = -1e30f; eB[nb][0] = -1e30f; }
                if (mm.y == 0) { eA[nb][1] = -1e30f; eB[nb][1] = -1e30f; }
                if (mm.z == 0) { eA[nb][2] = -1e30f; eB[nb][2] = -1e30f; }
                if (mm.w == 0) { eA[nb][3] = -1e30f; eB[nb][3] = -1e30f; }
            }
        }
        // no-max softmax: P = exp2(S); pack pairs, b64 LDS write
#pragma unroll
        for (int nb = 0; nb < 4; ++nb) {
            float a0 = __builtin_amdgcn_exp2f(eA[nb][0]);
            float a1 = __builtin_amdgcn_exp2f(eA[nb][1]);
            float a2 = __builtin_amdgcn_exp2f(eA[nb][2]);
            float a3 = __builtin_amdgcn_exp2f(eA[nb][3]);
            laccA += (a0 + a1) + (a2 + a3);
            uint2 pka;
            pka.x = cvt_pk_bf16(a0, a1);
            pka.y = cvt_pk_bf16(a2, a3);
            *(uint2*)(&plds[w][0][lo][16 * nb + 4 * hi]) = pka;

            float b0 = __builtin_amdgcn_exp2f(eB[nb][0]);
            float b1 = __builtin_amdgcn_exp2f(eB[nb][1]);
            float b2 = __builtin_amdgcn_exp2f(eB[nb][2]);
            float b3 = __builtin_amdgcn_exp2f(eB[nb][3]);
            laccB += (b0 + b1) + (b2 + b3);
            uint2 pkb;
            pkb.x = cvt_pk_bf16(b0, b1);
            pkb.y = cvt_pk_bf16(b2, b3);
            *(uint2*)(&plds[w][1][lo][16 * nb + 4 * hi]) = pkb;
        }
        // P^T B-fragments via per-wave LDS round-trip (same-wave ordering)
        short8 paA0 = *(const short8*)(&plds[w][0][lo][hi * 8]);
        short8 paA1 = *(const short8*)(&plds[w][0][lo][32 + hi * 8]);
        short8 paB0 = *(const short8*)(&plds[w][1][lo][hi * 8]);
        short8 paB1 = *(const short8*)(&plds[w][1][lo][32 + hi * 8]);
        // O^T += V^T P^T (V fragments shared)
#pragma unroll
        for (int nb = 0; nb < 4; ++nb) {
            oA[nb] = MFMA(va0[nb], paA0, oA[nb]);
            oA[nb] = MFMA(va1[nb], paA1, oA[nb]);
            oB[nb] = MFMA(va0[nb], paB0, oB[nb]);
            oB[nb] = MFMA(va1[nb], paB1, oB[nb]);
        }
    }

    laccA += __shfl_xor(laccA, 16);
    laccA += __shfl_xor(laccA, 32);
    laccB += __shfl_xor(laccB, 16);
    laccB += __shfl_xor(laccB, 32);
    const float linvA = 1.0f / laccA;
    const float linvB = 1.0f / laccB;

    // lane (lo,hi) holds O^T[d=16nb+4hi+i][q] -> ao[q][h*64 + d]
    unsigned short* opA = ao_ws + ((size_t)n * SEQ + q0 + lo) * EMB + h * HD;
    unsigned short* opB = ao_ws + ((size_t)n * SEQ + q0 + 16 + lo) * EMB + h * HD;
#pragma unroll
    for (int nb = 0; nb < 4; ++nb) {
        ushort4_t pa, pb;
        pa[0] = f2bf(oA[nb][0] * linvA); pa[1] = f2bf(oA[nb][1] * linvA);
        pa[2] = f2bf(oA[nb][2] * linvA); pa[3] = f2bf(oA[nb][3] * linvA);
        *(ushort4_t*)(opA + 16 * nb + 4 * hi) = pa;
        pb[0] = f2bf(oB[nb][0] * linvB); pb[1] = f2bf(oB[nb][1] * linvB);
        pb[2] = f2bf(oB[nb][2] * linvB); pb[3] = f2bf(oB[nb][3] * linvB);
        *(ushort4_t*)(opB + 16 * nb + 4 * hi) = pb;
    }
}

// ---------------------------------------------------------------------------
// Kernel 4: output projection (unchanged)
// ---------------------------------------------------------------------------
__global__ __launch_bounds__(256) void out_proj_kernel(
    const unsigned short* __restrict__ ao_ws, const unsigned short* __restrict__ wob,
    const float* __restrict__ bo, float* __restrict__ out)
{
    const int bid = blockIdx.x;
    const int nc = bid & 7;
    const int mt = bid >> 3;
    const int lane = threadIdx.x & 63;
    const int w = threadIdx.x >> 6;
    const int lo = lane & 15, hi = lane >> 4;
    const int m0 = mt * 64 + w * 16;
    const int e0 = nc * 64;

    f32x4 acc[4];
#pragma unroll
    for (int nb = 0; nb < 4; ++nb) acc[nb] = (f32x4){0.f, 0.f, 0.f, 0.f};

    const unsigned short* ar = ao_ws + (size_t)(m0 + lo) * EMB;
    for (int k0 = 0; k0 < EMB; k0 += 32) {
        short8 a = *(const short8*)(ar + k0 + hi * 8);
#pragma unroll
        for (int nb = 0; nb < 4; ++nb) {
            short8 b = *(const short8*)(wob + (size_t)(e0 + lo + 16 * nb) * EMB + k0 + hi * 8);
            acc[nb] = MFMA(a, b, acc[nb]);
        }
    }
#pragma unroll
    for (int nb = 0; nb < 4; ++nb) {
        float bias = bo[e0 + lo + 16 * nb];
#pragma unroll
        for (int i = 0; i < 4; ++i)
            out[(size_t)(m0 + hi * 4 + i) * EMB + e0 + lo + 16 * nb] = acc[nb][i] + bias;
    }
}

// ---------------------------------------------------------------------------
extern "C" void kernel_launch(void* const* d_in, const int* in_sizes, int n_in,
                              void* d_out, int out_size, void* d_ws, size_t ws_size,
                              hipStream_t stream)
{
    const float* vin = (const float*)d_in[0];
    const float* kin = (const float*)d_in[1];
    const float* qin = (const float*)d_in[2];
    const int*  mask = (const int*)d_in[3];
    const float* Wv  = (const float*)d_in[4];
    const float* Wk  = (const float*)d_in[5];
    const float* Wq  = (const float*)d_in[6];
    const float* Wo  = (const float*)d_in[7];
    const float* bo  = (const float*)d_in[8];
    float* out = (float*)d_out;

    const int N = in_sizes[0] / (SEQ * EMB);   // 4

    char* ws = (char*)d_ws;
    const size_t qkv_bytes = (size_t)N * NHEADS * SEQ * HD * 2;  // 8.39 MB each
    unsigned short* q_ws  = (unsigned short*)(ws);
    unsigned short* k_ws  = (unsigned short*)(ws + qkv_bytes);
    unsigned short* vt_ws = (unsigned short*)(ws + 2 * qkv_bytes);
    unsigned short* ao_ws = (unsigned short*)(ws + 3 * qkv_bytes);
    unsigned short* wob   = (unsigned short*)(ws + 4 * qkv_bytes);
    unsigned*       flags = (unsigned*)(ws + 4 * qkv_bytes + (size_t)EMB * EMB * 2);

    hipLaunchKernelGGL(wconv_kernel, dim3(EMB * EMB / 2048), dim3(256), 0, stream,
                       Wo, wob);
    hipLaunchKernelGGL(maskflags_kernel, dim3(N), dim3(64), 0, stream,
                       mask, flags);
    hipLaunchKernelGGL(qkv_proj_kernel, dim3(N * NHEADS * (SEQ / 64), 3), dim3(256), 0, stream,
                       vin, kin, qin, Wv, Wk, Wq, q_ws, k_ws, vt_ws);
    hipLaunchKernelGGL(attn_kernel, dim3(N * NHEADS * (SEQ / 32) / 4), dim3(256), 0, stream,
                       q_ws, k_ws, vt_ws, mask, flags, ao_ws);
    hipLaunchKernelGGL(out_proj_kernel, dim3((N * SEQ / 64) * (EMB / 64)), dim3(256), 0, stream,
                       ao_ws, wob, bo, out);
}

// Round 10
// 145.775 us; speedup vs baseline: 6.0178x; 1.3699x over previous
//
#include <hip/hip_runtime.h>
#include <hip/hip_bf16.h>

#define EMB 512
#define NHEADS 8
#define HD 64
#define SEQ 2048

typedef float f32x4 __attribute__((ext_vector_type(4)));
typedef short short8 __attribute__((ext_vector_type(8)));
typedef unsigned short ushort4_t __attribute__((ext_vector_type(4)));

#define MFMA(a, b, c) __builtin_amdgcn_mfma_f32_16x16x32_bf16((a), (b), (c), 0, 0, 0)

__device__ inline unsigned short f2bf(float f) {
    union { float f; unsigned u; } v; v.f = f;
    unsigned r = v.u + 0x7fffu + ((v.u >> 16) & 1u);   // round-to-nearest-even
    return (unsigned short)(r >> 16);
}

__device__ inline unsigned cvt_pk_bf16(float a, float b) {
    unsigned r;
    asm("v_cvt_pk_bf16_f32 %0, %1, %2" : "=v"(r) : "v"(a), "v"(b));
    return r;  // low16 = bf16(a), high16 = bf16(b)
}

__device__ inline short8 f8_to_bf8(float4 a, float4 b) {
    short8 r;
    r[0] = (short)f2bf(a.x); r[1] = (short)f2bf(a.y);
    r[2] = (short)f2bf(a.z); r[3] = (short)f2bf(a.w);
    r[4] = (short)f2bf(b.x); r[5] = (short)f2bf(b.y);
    r[6] = (short)f2bf(b.z); r[7] = (short)f2bf(b.w);
    return r;
}

// ---------------------------------------------------------------------------
// Kernel 1: per-head QKV projection (unchanged, known-good)
// ---------------------------------------------------------------------------
__global__ __launch_bounds__(256) void qkv_proj_kernel(
    const float* __restrict__ vin, const float* __restrict__ kin,
    const float* __restrict__ qin,
    const float* __restrict__ Wv, const float* __restrict__ Wk,
    const float* __restrict__ Wq,
    unsigned short* __restrict__ q_ws, unsigned short* __restrict__ k_ws,
    unsigned short* __restrict__ vt_ws)
{
    const int z = blockIdx.y;
    const float* __restrict__ x = (z == 0) ? qin : (z == 1 ? kin : vin);
    const float* __restrict__ W = (z == 0) ? Wq : (z == 1 ? Wk : Wv);

    const int bid = blockIdx.x;
    const int st = bid & 31;
    const int h  = (bid >> 5) & 7;
    const int n  = bid >> 8;

    const int lane = threadIdx.x & 63;
    const int w    = threadIdx.x >> 6;
    const int lo = lane & 15, hi = lane >> 4;
    const int s_base = st * 64 + w * 16;

    const float* xr = x + ((size_t)n * SEQ + s_base + lo) * EMB + h * HD;
    short8 a[2];
#pragma unroll
    for (int kb = 0; kb < 2; ++kb) {
        const float4* p = (const float4*)(xr + kb * 32 + hi * 8);
        a[kb] = f8_to_bf8(p[0], p[1]);
    }
    short8 b[2][4];
#pragma unroll
    for (int nb = 0; nb < 4; ++nb) {
        const float* wr = W + (lo + 16 * nb) * HD;
#pragma unroll
        for (int kb = 0; kb < 2; ++kb) {
            const float4* p = (const float4*)(wr + kb * 32 + hi * 8);
            b[kb][nb] = f8_to_bf8(p[0], p[1]);
        }
    }
    f32x4 acc[4];
#pragma unroll
    for (int nb = 0; nb < 4; ++nb) {
        f32x4 t = {0.f, 0.f, 0.f, 0.f};
        t = MFMA(a[0], b[0][nb], t);
        t = MFMA(a[1], b[1][nb], t);
        acc[nb] = t;
    }
    const size_t nh = (size_t)n * NHEADS + h;
    if (z < 2) {
        const float sc = (z == 0) ? 0.18033688011112042f : 1.0f; // log2(e)/8
        unsigned short* o = (z == 0 ? q_ws : k_ws) + nh * SEQ * HD;
#pragma unroll
        for (int nb = 0; nb < 4; ++nb)
#pragma unroll
            for (int i = 0; i < 4; ++i)
                o[(size_t)(s_base + hi * 4 + i) * HD + lo + 16 * nb] =
                    f2bf(acc[nb][i] * sc);
    } else {
        unsigned short* o = vt_ws + nh * HD * SEQ;
#pragma unroll
        for (int nb = 0; nb < 4; ++nb) {
            ushort4_t pk;
            pk[0] = f2bf(acc[nb][0]); pk[1] = f2bf(acc[nb][1]);
            pk[2] = f2bf(acc[nb][2]); pk[3] = f2bf(acc[nb][3]);
            *(ushort4_t*)(o + (size_t)(lo + 16 * nb) * SEQ + s_base + hi * 4) = pk;
        }
    }
}

// ---------------------------------------------------------------------------
// Kernel 2: Wo fp32 -> bf16 (unchanged)
// ---------------------------------------------------------------------------
__global__ __launch_bounds__(256) void wconv_kernel(
    const float* __restrict__ Wo, unsigned short* __restrict__ wob)
{
    const int idx = (blockIdx.x * 256 + threadIdx.x) * 8;
    const float4* p = (const float4*)(Wo + idx);
    short8 r = f8_to_bf8(p[0], p[1]);
    *(short8*)(wob + idx) = r;
}

// ---------------------------------------------------------------------------
// Kernel 2b: per-(n, 64-key-tile) mask-zero flags (unchanged)
// ---------------------------------------------------------------------------
__global__ __launch_bounds__(64) void maskflags_kernel(
    const int* __restrict__ mask, unsigned* __restrict__ flags)
{
    const int n = blockIdx.x;
    const int t = threadIdx.x;           // 64 threads; 0..31 scan tiles
    bool has0 = false;
    if (t < 32) {
        const int* mrow = mask + (size_t)n * SEQ + t * 64;
#pragma unroll 4
        for (int j = 0; j < 64; j += 4) {
            int4 m4 = *(const int4*)(mrow + j);
            has0 |= (m4.x == 0) | (m4.y == 0) | (m4.z == 0) | (m4.w == 0);
        }
    }
    unsigned long long b = __ballot(has0);
    if (t == 0) flags[n] = (unsigned)(b & 0xffffffffu);
}

// ---------------------------------------------------------------------------
// Kernel 3: flash attention, 4 q-tiles (64 q-rows) per wave.
// One 16KB K/V tile read feeds 64 MFMAs (4 independent per-qi chains,
// each QK->softmax->plds->PV; K/V fragments loaded once at top).
// L2-byte traffic per unit work halved vs round 9 (the proven binding
// resource: ~14 B/cyc/CU L2 delivery). No inter-wave sharing, no barriers.
// ---------------------------------------------------------------------------
__global__ __launch_bounds__(256, 1) void attn_kernel(
    const unsigned short* __restrict__ q_ws, const unsigned short* __restrict__ k_ws,
    const unsigned short* __restrict__ vt_ws, const int* __restrict__ mask,
    const unsigned* __restrict__ flags, unsigned short* __restrict__ ao_ws)
{
    __shared__ __align__(16) unsigned short plds[4][4][16][72];

    const int lane = threadIdx.x & 63;
    const int w = threadIdx.x >> 6;
    const int lo = lane & 15, hi = lane >> 4;
    // XCD swizzle, grid=256 (bijective): 32 blocks/XCD, each (n,h)'s 8 blocks
    // and 512KB K/V stream pinned to one XCD's L2.
    const int bid = (blockIdx.x & 7) * 32 + (blockIdx.x >> 3);
    const int wid = bid * 4 + w;
    const int qt4 = wid & 31;          // 64-row q-block index (S/64 = 32)
    const int h   = (wid >> 5) & 7;
    const int n   = wid >> 8;
    const size_t nh = (size_t)n * NHEADS + h;

    const unsigned short* qp = q_ws + nh * SEQ * HD;
    const unsigned short* kp = k_ws + nh * SEQ * HD;
    const unsigned short* vp = vt_ws + nh * HD * SEQ;
    const int* mp = mask + (size_t)n * SEQ;
    const unsigned fl = flags[n];

    const int q0 = qt4 * 64;
    short8 aq[4][2];
#pragma unroll
    for (int qi = 0; qi < 4; ++qi)
#pragma unroll
        for (int kb = 0; kb < 2; ++kb)
            aq[qi][kb] = *(const short8*)(qp + (size_t)(q0 + 16 * qi + lo) * HD
                                          + kb * 32 + hi * 8);

    f32x4 o[4][4];
    float lacc[4] = {0.f, 0.f, 0.f, 0.f};
#pragma unroll
    for (int qi = 0; qi < 4; ++qi)
#pragma unroll
        for (int nb = 0; nb < 4; ++nb)
            o[qi][nb] = (f32x4){0.f, 0.f, 0.f, 0.f};

    for (int t = 0; t < 32; ++t) {
        const int kt = t * 64;
        // shared K and V^T fragments for this tile (16 x 16B loads)
        short8 k0[4], k1[4], va0[4], va1[4];
#pragma unroll
        for (int nb = 0; nb < 4; ++nb) {
            const unsigned short* vr = vp + (size_t)(16 * nb + lo) * SEQ + kt + hi * 8;
            va0[nb] = *(const short8*)vr;
            va1[nb] = *(const short8*)(vr + 32);
            const unsigned short* kr = kp + (size_t)(kt + 16 * nb + lo) * HD + hi * 8;
            k0[nb] = *(const short8*)kr;
            k1[nb] = *(const short8*)(kr + 32);
        }
        const bool masked = (fl >> t) & 1u;
        // 4 independent per-qi chains; scheduler interleaves them
#pragma unroll
        for (int qi = 0; qi < 4; ++qi) {
            // S^T = K Q^T : D[key][q]; lane holds keys 16nb+4hi+i for q=lo
            f32x4 e[4];
#pragma unroll
            for (int nb = 0; nb < 4; ++nb) {
                f32x4 tt = {0.f, 0.f, 0.f, 0.f};
                tt = MFMA(k0[nb], aq[qi][0], tt);
                tt = MFMA(k1[nb], aq[qi][1], tt);
                e[nb] = tt;
            }
            if (masked) {
#pragma unroll
                for (int nb = 0; nb < 4; ++nb) {
                    const int4 mm = *(const int4*)(mp + kt + 16 * nb + 4 * hi);
                    if (mm.x == 0) e[nb][0] = -1e30f;
                    if (mm.y == 0) e[nb][1] = -1e30f;
                    if (mm.z == 0) e[nb][2] = -1e30f;
                    if (mm.w == 0) e[nb][3] = -1e30f;
                }
            }
            // no-max softmax: P = exp2(S); pack pairs, b64 LDS write
#pragma unroll
            for (int nb = 0; nb < 4; ++nb) {
                float p0 = __builtin_amdgcn_exp2f(e[nb][0]);
                float p1 = __builtin_amdgcn_exp2f(e[nb][1]);
                float p2 = __builtin_amdgcn_exp2f(e[nb][2]);
                float p3 = __builtin_amdgcn_exp2f(e[nb][3]);
                lacc[qi] += (p0 + p1) + (p2 + p3);
                uint2 pk;
                pk.x = cvt_pk_bf16(p0, p1);
                pk.y = cvt_pk_bf16(p2, p3);
                *(uint2*)(&plds[w][qi][lo][16 * nb + 4 * hi]) = pk;
            }
            // P^T B-fragments via per-wave LDS round-trip (same-wave ordering)
            short8 pa0 = *(const short8*)(&plds[w][qi][lo][hi * 8]);
            short8 pa1 = *(const short8*)(&plds[w][qi][lo][32 + hi * 8]);
            // O^T += V^T P^T (V fragments shared across qi)
#pragma unroll
            for (int nb = 0; nb < 4; ++nb) {
                o[qi][nb] = MFMA(va0[nb], pa0, o[qi][nb]);
                o[qi][nb] = MFMA(va1[nb], pa1, o[qi][nb]);
            }
        }
    }

#pragma unroll
    for (int qi = 0; qi < 4; ++qi) {
        lacc[qi] += __shfl_xor(lacc[qi], 16);
        lacc[qi] += __shfl_xor(lacc[qi], 32);
        const float linv = 1.0f / lacc[qi];
        // lane (lo,hi) holds O^T[d=16nb+4hi+i][q] -> ao[q][h*64 + d]
        unsigned short* op = ao_ws + ((size_t)n * SEQ + q0 + 16 * qi + lo) * EMB + h * HD;
#pragma unroll
        for (int nb = 0; nb < 4; ++nb) {
            ushort4_t pk;
            pk[0] = f2bf(o[qi][nb][0] * linv);
            pk[1] = f2bf(o[qi][nb][1] * linv);
            pk[2] = f2bf(o[qi][nb][2] * linv);
            pk[3] = f2bf(o[qi][nb][3] * linv);
            *(ushort4_t*)(op + 16 * nb + 4 * hi) = pk;
        }
    }
}

// ---------------------------------------------------------------------------
// Kernel 4: output projection (unchanged)
// ---------------------------------------------------------------------------
__global__ __launch_bounds__(256) void out_proj_kernel(
    const unsigned short* __restrict__ ao_ws, const unsigned short* __restrict__ wob,
    const float* __restrict__ bo, float* __restrict__ out)
{
    const int bid = blockIdx.x;
    const int nc = bid & 7;
    const int mt = bid >> 3;
    const int lane = threadIdx.x & 63;
    const int w = threadIdx.x >> 6;
    const int lo = lane & 15, hi = lane >> 4;
    const int m0 = mt * 64 + w * 16;
    const int e0 = nc * 64;

    f32x4 acc[4];
#pragma unroll
    for (int nb = 0; nb < 4; ++nb) acc[nb] = (f32x4){0.f, 0.f, 0.f, 0.f};

    const unsigned short* ar = ao_ws + (size_t)(m0 + lo) * EMB;
    for (int k0 = 0; k0 < EMB; k0 += 32) {
        short8 a = *(const short8*)(ar + k0 + hi * 8);
#pragma unroll
        for (int nb = 0; nb < 4; ++nb) {
            short8 b = *(const short8*)(wob + (size_t)(e0 + lo + 16 * nb) * EMB + k0 + hi * 8);
            acc[nb] = MFMA(a, b, acc[nb]);
        }
    }
#pragma unroll
    for (int nb = 0; nb < 4; ++nb) {
        float bias = bo[e0 + lo + 16 * nb];
#pragma unroll
        for (int i = 0; i < 4; ++i)
            out[(size_t)(m0 + hi * 4 + i) * EMB + e0 + lo + 16 * nb] = acc[nb][i] + bias;
    }
}

// ---------------------------------------------------------------------------
extern "C" void kernel_launch(void* const* d_in, const int* in_sizes, int n_in,
                              void* d_out, int out_size, void* d_ws, size_t ws_size,
                              hipStream_t stream)
{
    const float* vin = (const float*)d_in[0];
    const float* kin = (const float*)d_in[1];
    const float* qin = (const float*)d_in[2];
    const int*  mask = (const int*)d_in[3];
    const float* Wv  = (const float*)d_in[4];
    const float* Wk  = (const float*)d_in[5];
    const float* Wq  = (const float*)d_in[6];
    const float* Wo  = (const float*)d_in[7];
    const float* bo  = (const float*)d_in[8];
    float* out = (float*)d_out;

    const int N = in_sizes[0] / (SEQ * EMB);   // 4

    char* ws = (char*)d_ws;
    const size_t qkv_bytes = (size_t)N * NHEADS * SEQ * HD * 2;  // 8.39 MB each
    unsigned short* q_ws  = (unsigned short*)(ws);
    unsigned short* k_ws  = (unsigned short*)(ws + qkv_bytes);
    unsigned short* vt_ws = (unsigned short*)(ws + 2 * qkv_bytes);
    unsigned short* ao_ws = (unsigned short*)(ws + 3 * qkv_bytes);
    unsigned short* wob   = (unsigned short*)(ws + 4 * qkv_bytes);
    unsigned*       flags = (unsigned*)(ws + 4 * qkv_bytes + (size_t)EMB * EMB * 2);

    hipLaunchKernelGGL(wconv_kernel, dim3(EMB * EMB / 2048), dim3(256), 0, stream,
                       Wo, wob);
    hipLaunchKernelGGL(maskflags_kernel, dim3(N), dim3(64), 0, stream,
                       mask, flags);
    hipLaunchKernelGGL(qkv_proj_kernel, dim3(N * NHEADS * (SEQ / 64), 3), dim3(256), 0, stream,
                       vin, kin, qin, Wv, Wk, Wq, q_ws, k_ws, vt_ws);
    hipLaunchKernelGGL(attn_kernel, dim3(N * NHEADS * (SEQ / 64) / 4), dim3(256), 0, stream,
                       q_ws, k_ws, vt_ws, mask, flags, ao_ws);
    hipLaunchKernelGGL(out_proj_kernel, dim3((N * SEQ / 64) * (EMB / 64)), dim3(256), 0, stream,
                       ao_ws, wob, bo, out);
}

// Round 11
// 143.750 us; speedup vs baseline: 6.1026x; 1.0141x over previous
//
#include <hip/hip_runtime.h>
#include <hip/hip_bf16.h>

#define EMB 512
#define NHEADS 8
#define HD 64
#define SEQ 2048

typedef float f32x4 __attribute__((ext_vector_type(4)));
typedef short short8 __attribute__((ext_vector_type(8)));
typedef unsigned short ushort4_t __attribute__((ext_vector_type(4)));

#define MFMA(a, b, c) __builtin_amdgcn_mfma_f32_16x16x32_bf16((a), (b), (c), 0, 0, 0)

__device__ inline unsigned short f2bf(float f) {
    union { float f; unsigned u; } v; v.f = f;
    unsigned r = v.u + 0x7fffu + ((v.u >> 16) & 1u);   // round-to-nearest-even
    return (unsigned short)(r >> 16);
}

__device__ inline unsigned cvt_pk_bf16(float a, float b) {
    unsigned r;
    asm("v_cvt_pk_bf16_f32 %0, %1, %2" : "=v"(r) : "v"(a), "v"(b));
    return r;  // low16 = bf16(a), high16 = bf16(b)
}

__device__ inline short8 f8_to_bf8(float4 a, float4 b) {
    short8 r;
    r[0] = (short)f2bf(a.x); r[1] = (short)f2bf(a.y);
    r[2] = (short)f2bf(a.z); r[3] = (short)f2bf(a.w);
    r[4] = (short)f2bf(b.x); r[5] = (short)f2bf(b.y);
    r[6] = (short)f2bf(b.z); r[7] = (short)f2bf(b.w);
    return r;
}

// ---------------------------------------------------------------------------
// Kernel 1: per-head QKV projection (unchanged, known-good)
// ---------------------------------------------------------------------------
__global__ __launch_bounds__(256) void qkv_proj_kernel(
    const float* __restrict__ vin, const float* __restrict__ kin,
    const float* __restrict__ qin,
    const float* __restrict__ Wv, const float* __restrict__ Wk,
    const float* __restrict__ Wq,
    unsigned short* __restrict__ q_ws, unsigned short* __restrict__ k_ws,
    unsigned short* __restrict__ vt_ws)
{
    const int z = blockIdx.y;
    const float* __restrict__ x = (z == 0) ? qin : (z == 1 ? kin : vin);
    const float* __restrict__ W = (z == 0) ? Wq : (z == 1 ? Wk : Wv);

    const int bid = blockIdx.x;
    const int st = bid & 31;
    const int h  = (bid >> 5) & 7;
    const int n  = bid >> 8;

    const int lane = threadIdx.x & 63;
    const int w    = threadIdx.x >> 6;
    const int lo = lane & 15, hi = lane >> 4;
    const int s_base = st * 64 + w * 16;

    const float* xr = x + ((size_t)n * SEQ + s_base + lo) * EMB + h * HD;
    short8 a[2];
#pragma unroll
    for (int kb = 0; kb < 2; ++kb) {
        const float4* p = (const float4*)(xr + kb * 32 + hi * 8);
        a[kb] = f8_to_bf8(p[0], p[1]);
    }
    short8 b[2][4];
#pragma unroll
    for (int nb = 0; nb < 4; ++nb) {
        const float* wr = W + (lo + 16 * nb) * HD;
#pragma unroll
        for (int kb = 0; kb < 2; ++kb) {
            const float4* p = (const float4*)(wr + kb * 32 + hi * 8);
            b[kb][nb] = f8_to_bf8(p[0], p[1]);
        }
    }
    f32x4 acc[4];
#pragma unroll
    for (int nb = 0; nb < 4; ++nb) {
        f32x4 t = {0.f, 0.f, 0.f, 0.f};
        t = MFMA(a[0], b[0][nb], t);
        t = MFMA(a[1], b[1][nb], t);
        acc[nb] = t;
    }
    const size_t nh = (size_t)n * NHEADS + h;
    if (z < 2) {
        const float sc = (z == 0) ? 0.18033688011112042f : 1.0f; // log2(e)/8
        unsigned short* o = (z == 0 ? q_ws : k_ws) + nh * SEQ * HD;
#pragma unroll
        for (int nb = 0; nb < 4; ++nb)
#pragma unroll
            for (int i = 0; i < 4; ++i)
                o[(size_t)(s_base + hi * 4 + i) * HD + lo + 16 * nb] =
                    f2bf(acc[nb][i] * sc);
    } else {
        unsigned short* o = vt_ws + nh * HD * SEQ;
#pragma unroll
        for (int nb = 0; nb < 4; ++nb) {
            ushort4_t pk;
            pk[0] = f2bf(acc[nb][0]); pk[1] = f2bf(acc[nb][1]);
            pk[2] = f2bf(acc[nb][2]); pk[3] = f2bf(acc[nb][3]);
            *(ushort4_t*)(o + (size_t)(lo + 16 * nb) * SEQ + s_base + hi * 4) = pk;
        }
    }
}

// ---------------------------------------------------------------------------
// Kernel 2: Wo fp32 -> bf16 (unchanged)
// ---------------------------------------------------------------------------
__global__ __launch_bounds__(256) void wconv_kernel(
    const float* __restrict__ Wo, unsigned short* __restrict__ wob)
{
    const int idx = (blockIdx.x * 256 + threadIdx.x) * 8;
    const float4* p = (const float4*)(Wo + idx);
    short8 r = f8_to_bf8(p[0], p[1]);
    *(short8*)(wob + idx) = r;
}

// ---------------------------------------------------------------------------
// Kernel 2b: per-(n, 64-key-tile) mask-zero flags (unchanged)
// ---------------------------------------------------------------------------
__global__ __launch_bounds__(64) void maskflags_kernel(
    const int* __restrict__ mask, unsigned* __restrict__ flags)
{
    const int n = blockIdx.x;
    const int t = threadIdx.x;           // 64 threads; 0..31 scan tiles
    bool has0 = false;
    if (t < 32) {
        const int* mrow = mask + (size_t)n * SEQ + t * 64;
#pragma unroll 4
        for (int j = 0; j < 64; j += 4) {
            int4 m4 = *(const int4*)(mrow + j);
            has0 |= (m4.x == 0) | (m4.y == 0) | (m4.z == 0) | (m4.w == 0);
        }
    }
    unsigned long long b = __ballot(has0);
    if (t == 0) flags[n] = (unsigned)(b & 0xffffffffu);
}

// ---------------------------------------------------------------------------
// Kernel 3: flash attention, 4 q-tiles/wave + block-cooperative LDS staging.
// Simplest-possible sync: single K/V buffer, TWO barriers per tile
//   barrier(A): all waves finished reading tile t-1
//   store prefetched regs -> LDS
//   barrier(B): tile t visible
//   issue global prefetch of tile t+1 (named regs; hides under compute)
//   compute tile t (K/V fragments read from LDS once, shared by 4 qi chains)
// Per-wave global loads drop 16 -> 4 per tile (the proven binding resource).
// ---------------------------------------------------------------------------
__global__ __launch_bounds__(256, 1) void attn_kernel(
    const unsigned short* __restrict__ q_ws, const unsigned short* __restrict__ k_ws,
    const unsigned short* __restrict__ vt_ws, const int* __restrict__ mask,
    const unsigned* __restrict__ flags, unsigned short* __restrict__ ao_ws)
{
    __shared__ __align__(16) unsigned short klds[64][72];  // [key][d], padded
    __shared__ __align__(16) unsigned short vlds[64][72];  // [d][key], padded
    __shared__ __align__(16) int            mlds[64];
    __shared__ __align__(16) unsigned short plds[4][4][16][72];

    const int lane = threadIdx.x & 63;
    const int w = threadIdx.x >> 6;
    const int lo = lane & 15, hi = lane >> 4;
    // XCD swizzle, grid=256 (bijective): 32 blocks/XCD; each (n,h)'s 8 blocks
    // and 512KB K/V stream pinned to one XCD's L2.
    const int bid = (blockIdx.x & 7) * 32 + (blockIdx.x >> 3);
    const int wid = bid * 4 + w;
    const int qt4 = wid & 31;          // 64-row q-block index (S/64 = 32)
    const int h   = (wid >> 5) & 7;
    const int n   = wid >> 8;
    const size_t nh = (size_t)n * NHEADS + h;

    const unsigned short* qp = q_ws + nh * SEQ * HD;
    const unsigned short* kp = k_ws + nh * SEQ * HD;
    const unsigned short* vp = vt_ws + nh * HD * SEQ;
    const int* mp = mask + (size_t)n * SEQ;
    const unsigned fl = flags[n];

    const int q0 = qt4 * 64;
    short8 aq[4][2];
#pragma unroll
    for (int qi = 0; qi < 4; ++qi)
#pragma unroll
        for (int kb = 0; kb < 2; ++kb)
            aq[qi][kb] = *(const short8*)(qp + (size_t)(q0 + 16 * qi + lo) * HD
                                          + kb * 32 + hi * 8);

    f32x4 o[4][4];
    float lacc[4] = {0.f, 0.f, 0.f, 0.f};
#pragma unroll
    for (int qi = 0; qi < 4; ++qi)
#pragma unroll
        for (int nb = 0; nb < 4; ++nb)
            o[qi][nb] = (f32x4){0.f, 0.f, 0.f, 0.f};

    // staging geometry: wave w owns rows [16w, 16w+16) of both K and V^T.
    // lane l covers rows 16w + (l>>3) and 16w + 8 + (l>>3), col chunk (l&7)*8.
    const int sr = 16 * w + (lane >> 3);      // first staged row
    const int sc = (lane & 7) * 8;            // staged col (shorts)

    // prologue: prefetch tile 0 into named regs
    short8 rka = *(const short8*)(kp + (size_t)(sr)     * HD + sc);
    short8 rkb = *(const short8*)(kp + (size_t)(sr + 8) * HD + sc);
    short8 rva = *(const short8*)(vp + (size_t)(sr)     * SEQ + sc);
    short8 rvb = *(const short8*)(vp + (size_t)(sr + 8) * SEQ + sc);
    int    rm  = (w == 0) ? mp[lane] : 0;

    for (int t = 0; t < 32; ++t) {
        const int kt = t * 64;
        __syncthreads();                      // (A) done reading tile t-1
        *(short8*)(&klds[sr][sc])     = rka;
        *(short8*)(&klds[sr + 8][sc]) = rkb;
        *(short8*)(&vlds[sr][sc])     = rva;
        *(short8*)(&vlds[sr + 8][sc]) = rvb;
        if (w == 0) mlds[lane] = rm;
        __syncthreads();                      // (B) tile t visible

        if (t < 31) {                         // prefetch tile t+1
            const int ktn = kt + 64;
            rka = *(const short8*)(kp + (size_t)(ktn + sr)     * HD + sc);
            rkb = *(const short8*)(kp + (size_t)(ktn + sr + 8) * HD + sc);
            rva = *(const short8*)(vp + (size_t)(sr)     * SEQ + ktn + sc);
            rvb = *(const short8*)(vp + (size_t)(sr + 8) * SEQ + ktn + sc);
            rm  = (w == 0) ? mp[ktn + lane] : 0;
        }

        // K and V^T fragments from LDS, once per tile, shared by all qi
        short8 k0[4], k1[4], va0[4], va1[4];
#pragma unroll
        for (int nb = 0; nb < 4; ++nb) {
            k0[nb]  = *(const short8*)(&klds[16 * nb + lo][hi * 8]);
            k1[nb]  = *(const short8*)(&klds[16 * nb + lo][32 + hi * 8]);
            va0[nb] = *(const short8*)(&vlds[16 * nb + lo][hi * 8]);
            va1[nb] = *(const short8*)(&vlds[16 * nb + lo][32 + hi * 8]);
        }
        const bool masked = (fl >> t) & 1u;
        // 4 independent per-qi chains
#pragma unroll
        for (int qi = 0; qi < 4; ++qi) {
            f32x4 e[4];
#pragma unroll
            for (int nb = 0; nb < 4; ++nb) {
                f32x4 tt = {0.f, 0.f, 0.f, 0.f};
                tt = MFMA(k0[nb], aq[qi][0], tt);
                tt = MFMA(k1[nb], aq[qi][1], tt);
                e[nb] = tt;
            }
            if (masked) {
#pragma unroll
                for (int nb = 0; nb < 4; ++nb) {
                    const int4 mm = *(const int4*)(&mlds[16 * nb + 4 * hi]);
                    if (mm.x == 0) e[nb][0] = -1e30f;
                    if (mm.y == 0) e[nb][1] = -1e30f;
                    if (mm.z == 0) e[nb][2] = -1e30f;
                    if (mm.w == 0) e[nb][3] = -1e30f;
                }
            }
#pragma unroll
            for (int nb = 0; nb < 4; ++nb) {
                float p0 = __builtin_amdgcn_exp2f(e[nb][0]);
                float p1 = __builtin_amdgcn_exp2f(e[nb][1]);
                float p2 = __builtin_amdgcn_exp2f(e[nb][2]);
                float p3 = __builtin_amdgcn_exp2f(e[nb][3]);
                lacc[qi] += (p0 + p1) + (p2 + p3);
                uint2 pk;
                pk.x = cvt_pk_bf16(p0, p1);
                pk.y = cvt_pk_bf16(p2, p3);
                *(uint2*)(&plds[w][qi][lo][16 * nb + 4 * hi]) = pk;
            }
            short8 pa0 = *(const short8*)(&plds[w][qi][lo][hi * 8]);
            short8 pa1 = *(const short8*)(&plds[w][qi][lo][32 + hi * 8]);
#pragma unroll
            for (int nb = 0; nb < 4; ++nb) {
                o[qi][nb] = MFMA(va0[nb], pa0, o[qi][nb]);
                o[qi][nb] = MFMA(va1[nb], pa1, o[qi][nb]);
            }
        }
    }

#pragma unroll
    for (int qi = 0; qi < 4; ++qi) {
        lacc[qi] += __shfl_xor(lacc[qi], 16);
        lacc[qi] += __shfl_xor(lacc[qi], 32);
        const float linv = 1.0f / lacc[qi];
        unsigned short* op = ao_ws + ((size_t)n * SEQ + q0 + 16 * qi + lo) * EMB + h * HD;
#pragma unroll
        for (int nb = 0; nb < 4; ++nb) {
            ushort4_t pk;
            pk[0] = f2bf(o[qi][nb][0] * linv);
            pk[1] = f2bf(o[qi][nb][1] * linv);
            pk[2] = f2bf(o[qi][nb][2] * linv);
            pk[3] = f2bf(o[qi][nb][3] * linv);
            *(ushort4_t*)(op + 16 * nb + 4 * hi) = pk;
        }
    }
}

// ---------------------------------------------------------------------------
// Kernel 4: output projection (unchanged)
// ---------------------------------------------------------------------------
__global__ __launch_bounds__(256) void out_proj_kernel(
    const unsigned short* __restrict__ ao_ws, const unsigned short* __restrict__ wob,
    const float* __restrict__ bo, float* __restrict__ out)
{
    const int bid = blockIdx.x;
    const int nc = bid & 7;
    const int mt = bid >> 3;
    const int lane = threadIdx.x & 63;
    const int w = threadIdx.x >> 6;
    const int lo = lane & 15, hi = lane >> 4;
    const int m0 = mt * 64 + w * 16;
    const int e0 = nc * 64;

    f32x4 acc[4];
#pragma unroll
    for (int nb = 0; nb < 4; ++nb) acc[nb] = (f32x4){0.f, 0.f, 0.f, 0.f};

    const unsigned short* ar = ao_ws + (size_t)(m0 + lo) * EMB;
    for (int k0 = 0; k0 < EMB; k0 += 32) {
        short8 a = *(const short8*)(ar + k0 + hi * 8);
#pragma unroll
        for (int nb = 0; nb < 4; ++nb) {
            short8 b = *(const short8*)(wob + (size_t)(e0 + lo + 16 * nb) * EMB + k0 + hi * 8);
            acc[nb] = MFMA(a, b, acc[nb]);
        }
    }
#pragma unroll
    for (int nb = 0; nb < 4; ++nb) {
        float bias = bo[e0 + lo + 16 * nb];
#pragma unroll
        for (int i = 0; i < 4; ++i)
            out[(size_t)(m0 + hi * 4 + i) * EMB + e0 + lo + 16 * nb] = acc[nb][i] + bias;
    }
}

// ---------------------------------------------------------------------------
extern "C" void kernel_launch(void* const* d_in, const int* in_sizes, int n_in,
                              void* d_out, int out_size, void* d_ws, size_t ws_size,
                              hipStream_t stream)
{
    const float* vin = (const float*)d_in[0];
    const float* kin = (const float*)d_in[1];
    const float* qin = (const float*)d_in[2];
    const int*  mask = (const int*)d_in[3];
    const float* Wv  = (const float*)d_in[4];
    const float* Wk  = (const float*)d_in[5];
    const float* Wq  = (const float*)d_in[6];
    const float* Wo  = (const float*)d_in[7];
    const float* bo  = (const float*)d_in[8];
    float* out = (float*)d_out;

    const int N = in_sizes[0] / (SEQ * EMB);   // 4

    char* ws = (char*)d_ws;
    const size_t qkv_bytes = (size_t)N * NHEADS * SEQ * HD * 2;  // 8.39 MB each
    unsigned short* q_ws  = (unsigned short*)(ws);
    unsigned short* k_ws  = (unsigned short*)(ws + qkv_bytes);
    unsigned short* vt_ws = (unsigned short*)(ws + 2 * qkv_bytes);
    unsigned short* ao_ws = (unsigned short*)(ws + 3 * qkv_bytes);
    unsigned short* wob   = (unsigned short*)(ws + 4 * qkv_bytes);
    unsigned*       flags = (unsigned*)(ws + 4 * qkv_bytes + (size_t)EMB * EMB * 2);

    hipLaunchKernelGGL(wconv_kernel, dim3(EMB * EMB / 2048), dim3(256), 0, stream,
                       Wo, wob);
    hipLaunchKernelGGL(maskflags_kernel, dim3(N), dim3(64), 0, stream,
                       mask, flags);
    hipLaunchKernelGGL(qkv_proj_kernel, dim3(N * NHEADS * (SEQ / 64), 3), dim3(256), 0, stream,
                       vin, kin, qin, Wv, Wk, Wq, q_ws, k_ws, vt_ws);
    hipLaunchKernelGGL(attn_kernel, dim3(N * NHEADS * (SEQ / 64) / 4), dim3(256), 0, stream,
                       q_ws, k_ws, vt_ws, mask, flags, ao_ws);
    hipLaunchKernelGGL(out_proj_kernel, dim3((N * SEQ / 64) * (EMB / 64)), dim3(256), 0, stream,
                       ao_ws, wob, bo, out);
}

// Round 12
// 132.568 us; speedup vs baseline: 6.6174x; 1.0843x over previous
//
#include <hip/hip_runtime.h>
#include <hip/hip_bf16.h>

#define EMB 512
#define NHEADS 8
#define HD 64
#define SEQ 2048

typedef float f32x4 __attribute__((ext_vector_type(4)));
typedef short short8 __attribute__((ext_vector_type(8)));
typedef unsigned short ushort4_t __attribute__((ext_vector_type(4)));

#define MFMA(a, b, c) __builtin_amdgcn_mfma_f32_16x16x32_bf16((a), (b), (c), 0, 0, 0)

__device__ inline unsigned short f2bf(float f) {
    union { float f; unsigned u; } v; v.f = f;
    unsigned r = v.u + 0x7fffu + ((v.u >> 16) & 1u);   // round-to-nearest-even
    return (unsigned short)(r >> 16);
}

__device__ inline unsigned cvt_pk_bf16(float a, float b) {
    unsigned r;
    asm("v_cvt_pk_bf16_f32 %0, %1, %2" : "=v"(r) : "v"(a), "v"(b));
    return r;  // low16 = bf16(a), high16 = bf16(b)
}

__device__ inline short8 f8_to_bf8(float4 a, float4 b) {
    short8 r;
    r[0] = (short)f2bf(a.x); r[1] = (short)f2bf(a.y);
    r[2] = (short)f2bf(a.z); r[3] = (short)f2bf(a.w);
    r[4] = (short)f2bf(b.x); r[5] = (short)f2bf(b.y);
    r[6] = (short)f2bf(b.z); r[7] = (short)f2bf(b.w);
    return r;
}

// ---------------------------------------------------------------------------
// Kernel 1: per-head QKV projection (unchanged, known-good)
// ---------------------------------------------------------------------------
__global__ __launch_bounds__(256) void qkv_proj_kernel(
    const float* __restrict__ vin, const float* __restrict__ kin,
    const float* __restrict__ qin,
    const float* __restrict__ Wv, const float* __restrict__ Wk,
    const float* __restrict__ Wq,
    unsigned short* __restrict__ q_ws, unsigned short* __restrict__ k_ws,
    unsigned short* __restrict__ vt_ws)
{
    const int z = blockIdx.y;
    const float* __restrict__ x = (z == 0) ? qin : (z == 1 ? kin : vin);
    const float* __restrict__ W = (z == 0) ? Wq : (z == 1 ? Wk : Wv);

    const int bid = blockIdx.x;
    const int st = bid & 31;
    const int h  = (bid >> 5) & 7;
    const int n  = bid >> 8;

    const int lane = threadIdx.x & 63;
    const int w    = threadIdx.x >> 6;
    const int lo = lane & 15, hi = lane >> 4;
    const int s_base = st * 64 + w * 16;

    const float* xr = x + ((size_t)n * SEQ + s_base + lo) * EMB + h * HD;
    short8 a[2];
#pragma unroll
    for (int kb = 0; kb < 2; ++kb) {
        const float4* p = (const float4*)(xr + kb * 32 + hi * 8);
        a[kb] = f8_to_bf8(p[0], p[1]);
    }
    short8 b[2][4];
#pragma unroll
    for (int nb = 0; nb < 4; ++nb) {
        const float* wr = W + (lo + 16 * nb) * HD;
#pragma unroll
        for (int kb = 0; kb < 2; ++kb) {
            const float4* p = (const float4*)(wr + kb * 32 + hi * 8);
            b[kb][nb] = f8_to_bf8(p[0], p[1]);
        }
    }
    f32x4 acc[4];
#pragma unroll
    for (int nb = 0; nb < 4; ++nb) {
        f32x4 t = {0.f, 0.f, 0.f, 0.f};
        t = MFMA(a[0], b[0][nb], t);
        t = MFMA(a[1], b[1][nb], t);
        acc[nb] = t;
    }
    const size_t nh = (size_t)n * NHEADS + h;
    if (z < 2) {
        const float sc = (z == 0) ? 0.18033688011112042f : 1.0f; // log2(e)/8
        unsigned short* o = (z == 0 ? q_ws : k_ws) + nh * SEQ * HD;
#pragma unroll
        for (int nb = 0; nb < 4; ++nb)
#pragma unroll
            for (int i = 0; i < 4; ++i)
                o[(size_t)(s_base + hi * 4 + i) * HD + lo + 16 * nb] =
                    f2bf(acc[nb][i] * sc);
    } else {
        unsigned short* o = vt_ws + nh * HD * SEQ;
#pragma unroll
        for (int nb = 0; nb < 4; ++nb) {
            ushort4_t pk;
            pk[0] = f2bf(acc[nb][0]); pk[1] = f2bf(acc[nb][1]);
            pk[2] = f2bf(acc[nb][2]); pk[3] = f2bf(acc[nb][3]);
            *(ushort4_t*)(o + (size_t)(lo + 16 * nb) * SEQ + s_base + hi * 4) = pk;
        }
    }
}

// ---------------------------------------------------------------------------
// Kernel 2: Wo fp32 -> bf16 (unchanged)
// ---------------------------------------------------------------------------
__global__ __launch_bounds__(256) void wconv_kernel(
    const float* __restrict__ Wo, unsigned short* __restrict__ wob)
{
    const int idx = (blockIdx.x * 256 + threadIdx.x) * 8;
    const float4* p = (const float4*)(Wo + idx);
    short8 r = f8_to_bf8(p[0], p[1]);
    *(short8*)(wob + idx) = r;
}

// ---------------------------------------------------------------------------
// Kernel 2b: per-(n, 64-key-tile) mask-zero flags (unchanged)
// ---------------------------------------------------------------------------
__global__ __launch_bounds__(64) void maskflags_kernel(
    const int* __restrict__ mask, unsigned* __restrict__ flags)
{
    const int n = blockIdx.x;
    const int t = threadIdx.x;           // 64 threads; 0..31 scan tiles
    bool has0 = false;
    if (t < 32) {
        const int* mrow = mask + (size_t)n * SEQ + t * 64;
#pragma unroll 4
        for (int j = 0; j < 64; j += 4) {
            int4 m4 = *(const int4*)(mrow + j);
            has0 |= (m4.x == 0) | (m4.y == 0) | (m4.z == 0) | (m4.w == 0);
        }
    }
    unsigned long long b = __ballot(has0);
    if (t == 0) flags[n] = (unsigned)(b & 0xffffffffu);
}

// ---------------------------------------------------------------------------
// Kernel 3: flash attention. 512-thread blocks (8 waves = 2 waves/SIMD for
// stall overlap — the proven binder at R11 was serial-chain exposure at
// 1 wave/SIMD), 2 q-tiles/wave, grid=256 (1 block/CU). Block-cooperative
// LDS staging (1 K-load + 1 V-load per thread per tile), single buffer,
// two barriers per tile, register prefetch of tile t+1 under compute.
// Swapped-operand QK^T, no-max softmax, per-wave LDS P-transpose.
// ---------------------------------------------------------------------------
__global__ __launch_bounds__(512, 2) void attn_kernel(
    const unsigned short* __restrict__ q_ws, const unsigned short* __restrict__ k_ws,
    const unsigned short* __restrict__ vt_ws, const int* __restrict__ mask,
    const unsigned* __restrict__ flags, unsigned short* __restrict__ ao_ws)
{
    __shared__ __align__(16) unsigned short klds[64][72];  // [key][d], padded
    __shared__ __align__(16) unsigned short vlds[64][72];  // [d][key], padded
    __shared__ __align__(16) int            mlds[64];
    __shared__ __align__(16) unsigned short plds[8][2][16][72];

    const int tid  = threadIdx.x;
    const int lane = tid & 63;
    const int w    = tid >> 6;                  // 0..7
    const int lo = lane & 15, hi = lane >> 4;
    // XCD swizzle, grid=256 (bijective): 32 blocks/XCD; each (n,h)'s 8 blocks
    // and 512KB K/V stream pinned to one XCD's L2.
    const int bid = (blockIdx.x & 7) * 32 + (blockIdx.x >> 3);
    const int wid = bid * 8 + w;
    const int qt2 = wid & 63;          // 32-row q-block index (S/32 = 64)
    const int h   = (wid >> 6) & 7;
    const int n   = wid >> 9;
    const size_t nh = (size_t)n * NHEADS + h;

    const unsigned short* qp = q_ws + nh * SEQ * HD;
    const unsigned short* kp = k_ws + nh * SEQ * HD;
    const unsigned short* vp = vt_ws + nh * HD * SEQ;
    const int* mp = mask + (size_t)n * SEQ;
    const unsigned fl = flags[n];

    const int q0 = qt2 * 32;
    short8 aq[2][2];
#pragma unroll
    for (int qi = 0; qi < 2; ++qi)
#pragma unroll
        for (int kb = 0; kb < 2; ++kb)
            aq[qi][kb] = *(const short8*)(qp + (size_t)(q0 + 16 * qi + lo) * HD
                                          + kb * 32 + hi * 8);

    f32x4 o[2][4];
    float lacc[2] = {0.f, 0.f};
#pragma unroll
    for (int qi = 0; qi < 2; ++qi)
#pragma unroll
        for (int nb = 0; nb < 4; ++nb)
            o[qi][nb] = (f32x4){0.f, 0.f, 0.f, 0.f};

    // staging geometry: 512 threads cover 64 rows x 8 col-chunks exactly once
    // for K and V^T each (1 load per array per thread per tile).
    const int sr = tid >> 3;                  // staged row 0..63
    const int sc = (tid & 7) * 8;             // staged col (shorts)

    // prologue: prefetch tile 0 into named regs
    short8 rk = *(const short8*)(kp + (size_t)sr * HD + sc);
    short8 rv = *(const short8*)(vp + (size_t)sr * SEQ + sc);
    int    rm = (w == 0) ? mp[lane] : 0;

    for (int t = 0; t < 32; ++t) {
        const int kt = t * 64;
        __syncthreads();                      // (A) done reading tile t-1
        *(short8*)(&klds[sr][sc]) = rk;
        *(short8*)(&vlds[sr][sc]) = rv;
        if (w == 0) mlds[lane] = rm;
        __syncthreads();                      // (B) tile t visible

        if (t < 31) {                         // prefetch tile t+1
            const int ktn = kt + 64;
            rk = *(const short8*)(kp + (size_t)(ktn + sr) * HD + sc);
            rv = *(const short8*)(vp + (size_t)sr * SEQ + ktn + sc);
            rm = (w == 0) ? mp[ktn + lane] : 0;
        }

        // K and V^T fragments from LDS, once per tile, shared by both qi
        short8 k0[4], k1[4], va0[4], va1[4];
#pragma unroll
        for (int nb = 0; nb < 4; ++nb) {
            k0[nb]  = *(const short8*)(&klds[16 * nb + lo][hi * 8]);
            k1[nb]  = *(const short8*)(&klds[16 * nb + lo][32 + hi * 8]);
            va0[nb] = *(const short8*)(&vlds[16 * nb + lo][hi * 8]);
            va1[nb] = *(const short8*)(&vlds[16 * nb + lo][32 + hi * 8]);
        }
        const bool masked = (fl >> t) & 1u;
        // 2 independent per-qi chains
#pragma unroll
        for (int qi = 0; qi < 2; ++qi) {
            f32x4 e[4];
#pragma unroll
            for (int nb = 0; nb < 4; ++nb) {
                f32x4 tt = {0.f, 0.f, 0.f, 0.f};
                tt = MFMA(k0[nb], aq[qi][0], tt);
                tt = MFMA(k1[nb], aq[qi][1], tt);
                e[nb] = tt;
            }
            if (masked) {
#pragma unroll
                for (int nb = 0; nb < 4; ++nb) {
                    const int4 mm = *(const int4*)(&mlds[16 * nb + 4 * hi]);
                    if (mm.x == 0) e[nb][0] = -1e30f;
                    if (mm.y == 0) e[nb][1] = -1e30f;
                    if (mm.z == 0) e[nb][2] = -1e30f;
                    if (mm.w == 0) e[nb][3] = -1e30f;
                }
            }
#pragma unroll
            for (int nb = 0; nb < 4; ++nb) {
                float p0 = __builtin_amdgcn_exp2f(e[nb][0]);
                float p1 = __builtin_amdgcn_exp2f(e[nb][1]);
                float p2 = __builtin_amdgcn_exp2f(e[nb][2]);
                float p3 = __builtin_amdgcn_exp2f(e[nb][3]);
                lacc[qi] += (p0 + p1) + (p2 + p3);
                uint2 pk;
                pk.x = cvt_pk_bf16(p0, p1);
                pk.y = cvt_pk_bf16(p2, p3);
                *(uint2*)(&plds[w][qi][lo][16 * nb + 4 * hi]) = pk;
            }
            short8 pa0 = *(const short8*)(&plds[w][qi][lo][hi * 8]);
            short8 pa1 = *(const short8*)(&plds[w][qi][lo][32 + hi * 8]);
#pragma unroll
            for (int nb = 0; nb < 4; ++nb) {
                o[qi][nb] = MFMA(va0[nb], pa0, o[qi][nb]);
                o[qi][nb] = MFMA(va1[nb], pa1, o[qi][nb]);
            }
        }
    }

#pragma unroll
    for (int qi = 0; qi < 2; ++qi) {
        lacc[qi] += __shfl_xor(lacc[qi], 16);
        lacc[qi] += __shfl_xor(lacc[qi], 32);
        const float linv = 1.0f / lacc[qi];
        unsigned short* op = ao_ws + ((size_t)n * SEQ + q0 + 16 * qi + lo) * EMB + h * HD;
#pragma unroll
        for (int nb = 0; nb < 4; ++nb) {
            ushort4_t pk;
            pk[0] = f2bf(o[qi][nb][0] * linv);
            pk[1] = f2bf(o[qi][nb][1] * linv);
            pk[2] = f2bf(o[qi][nb][2] * linv);
            pk[3] = f2bf(o[qi][nb][3] * linv);
            *(ushort4_t*)(op + 16 * nb + 4 * hi) = pk;
        }
    }
}

// ---------------------------------------------------------------------------
// Kernel 4: output projection (unchanged)
// ---------------------------------------------------------------------------
__global__ __launch_bounds__(256) void out_proj_kernel(
    const unsigned short* __restrict__ ao_ws, const unsigned short* __restrict__ wob,
    const float* __restrict__ bo, float* __restrict__ out)
{
    const int bid = blockIdx.x;
    const int nc = bid & 7;
    const int mt = bid >> 3;
    const int lane = threadIdx.x & 63;
    const int w = threadIdx.x >> 6;
    const int lo = lane & 15, hi = lane >> 4;
    const int m0 = mt * 64 + w * 16;
    const int e0 = nc * 64;

    f32x4 acc[4];
#pragma unroll
    for (int nb = 0; nb < 4; ++nb) acc[nb] = (f32x4){0.f, 0.f, 0.f, 0.f};

    const unsigned short* ar = ao_ws + (size_t)(m0 + lo) * EMB;
    for (int k0 = 0; k0 < EMB; k0 += 32) {
        short8 a = *(const short8*)(ar + k0 + hi * 8);
#pragma unroll
        for (int nb = 0; nb < 4; ++nb) {
            short8 b = *(const short8*)(wob + (size_t)(e0 + lo + 16 * nb) * EMB + k0 + hi * 8);
            acc[nb] = MFMA(a, b, acc[nb]);
        }
    }
#pragma unroll
    for (int nb = 0; nb < 4; ++nb) {
        float bias = bo[e0 + lo + 16 * nb];
#pragma unroll
        for (int i = 0; i < 4; ++i)
            out[(size_t)(m0 + hi * 4 + i) * EMB + e0 + lo + 16 * nb] = acc[nb][i] + bias;
    }
}

// ---------------------------------------------------------------------------
extern "C" void kernel_launch(void* const* d_in, const int* in_sizes, int n_in,
                              void* d_out, int out_size, void* d_ws, size_t ws_size,
                              hipStream_t stream)
{
    const float* vin = (const float*)d_in[0];
    const float* kin = (const float*)d_in[1];
    const float* qin = (const float*)d_in[2];
    const int*  mask = (const int*)d_in[3];
    const float* Wv  = (const float*)d_in[4];
    const float* Wk  = (const float*)d_in[5];
    const float* Wq  = (const float*)d_in[6];
    const float* Wo  = (const float*)d_in[7];
    const float* bo  = (const float*)d_in[8];
    float* out = (float*)d_out;

    const int N = in_sizes[0] / (SEQ * EMB);   // 4

    char* ws = (char*)d_ws;
    const size_t qkv_bytes = (size_t)N * NHEADS * SEQ * HD * 2;  // 8.39 MB each
    unsigned short* q_ws  = (unsigned short*)(ws);
    unsigned short* k_ws  = (unsigned short*)(ws + qkv_bytes);
    unsigned short* vt_ws = (unsigned short*)(ws + 2 * qkv_bytes);
    unsigned short* ao_ws = (unsigned short*)(ws + 3 * qkv_bytes);
    unsigned short* wob   = (unsigned short*)(ws + 4 * qkv_bytes);
    unsigned*       flags = (unsigned*)(ws + 4 * qkv_bytes + (size_t)EMB * EMB * 2);

    hipLaunchKernelGGL(wconv_kernel, dim3(EMB * EMB / 2048), dim3(256), 0, stream,
                       Wo, wob);
    hipLaunchKernelGGL(maskflags_kernel, dim3(N), dim3(64), 0, stream,
                       mask, flags);
    hipLaunchKernelGGL(qkv_proj_kernel, dim3(N * NHEADS * (SEQ / 64), 3), dim3(256), 0, stream,
                       vin, kin, qin, Wv, Wk, Wq, q_ws, k_ws, vt_ws);
    hipLaunchKernelGGL(attn_kernel, dim3(N * NHEADS * (SEQ / 32) / 8), dim3(512), 0, stream,
                       q_ws, k_ws, vt_ws, mask, flags, ao_ws);
    hipLaunchKernelGGL(out_proj_kernel, dim3((N * SEQ / 64) * (EMB / 64)), dim3(256), 0, stream,
                       ao_ws, wob, bo, out);
}

// Round 13
// 108.211 us; speedup vs baseline: 8.1069x; 1.2251x over previous
//
#include <hip/hip_runtime.h>
#include <hip/hip_bf16.h>

#define EMB 512
#define NHEADS 8
#define HD 64
#define SEQ 2048

typedef float f32x4 __attribute__((ext_vector_type(4)));
typedef short short8 __attribute__((ext_vector_type(8)));
typedef unsigned short ushort4_t __attribute__((ext_vector_type(4)));

#define MFMA(a, b, c) __builtin_amdgcn_mfma_f32_16x16x32_bf16((a), (b), (c), 0, 0, 0)

__device__ inline unsigned short f2bf(float f) {
    union { float f; unsigned u; } v; v.f = f;
    unsigned r = v.u + 0x7fffu + ((v.u >> 16) & 1u);   // round-to-nearest-even
    return (unsigned short)(r >> 16);
}

__device__ inline unsigned cvt_pk_bf16(float a, float b) {
    unsigned r;
    asm("v_cvt_pk_bf16_f32 %0, %1, %2" : "=v"(r) : "v"(a), "v"(b));
    return r;  // low16 = bf16(a), high16 = bf16(b)
}

__device__ inline short8 f8_to_bf8(float4 a, float4 b) {
    short8 r;
    r[0] = (short)f2bf(a.x); r[1] = (short)f2bf(a.y);
    r[2] = (short)f2bf(a.z); r[3] = (short)f2bf(a.w);
    r[4] = (short)f2bf(b.x); r[5] = (short)f2bf(b.y);
    r[6] = (short)f2bf(b.z); r[7] = (short)f2bf(b.w);
    return r;
}

// ---------------------------------------------------------------------------
// Kernel 1: per-head QKV projection, v2.
// Weights pre-converted to bf16 (wqkvb). 2 s-subtiles per wave: block covers
// 128 s-rows; B fragments loaded ONCE per thread, amortized over 2x MFMAs.
// grid.x = N*H*(S/128) = 512, grid.y = 3 (q,k,v).
// ---------------------------------------------------------------------------
__global__ __launch_bounds__(256) void qkv_proj_kernel(
    const float* __restrict__ vin, const float* __restrict__ kin,
    const float* __restrict__ qin, const unsigned short* __restrict__ wqkvb,
    unsigned short* __restrict__ q_ws, unsigned short* __restrict__ k_ws,
    unsigned short* __restrict__ vt_ws)
{
    const int z = blockIdx.y;
    const float* __restrict__ x = (z == 0) ? qin : (z == 1 ? kin : vin);
    const unsigned short* __restrict__ wb = wqkvb + z * HD * HD;

    const int bid = blockIdx.x;
    const int st = bid & 15;            // S/128 = 16 tiles
    const int h  = (bid >> 4) & 7;
    const int n  = bid >> 7;

    const int lane = threadIdx.x & 63;
    const int w    = threadIdx.x >> 6;
    const int lo = lane & 15, hi = lane >> 4;
    const int s_base = st * 128 + w * 32;   // wave covers 32 rows

    // B fragments (bf16, pre-converted): B[k][n=lo+16nb], row lo+16nb of W
    short8 b[2][4];
#pragma unroll
    for (int nb = 0; nb < 4; ++nb)
#pragma unroll
        for (int kb = 0; kb < 2; ++kb)
            b[kb][nb] = *(const short8*)(wb + (lo + 16 * nb) * HD + kb * 32 + hi * 8);

    // A fragments: 2 subtiles x 16 rows
    short8 a[2][2];
#pragma unroll
    for (int sub = 0; sub < 2; ++sub) {
        const float* xr = x + ((size_t)n * SEQ + s_base + 16 * sub + lo) * EMB + h * HD;
#pragma unroll
        for (int kb = 0; kb < 2; ++kb) {
            const float4* p = (const float4*)(xr + kb * 32 + hi * 8);
            a[sub][kb] = f8_to_bf8(p[0], p[1]);
        }
    }

    f32x4 acc[2][4];
#pragma unroll
    for (int sub = 0; sub < 2; ++sub)
#pragma unroll
        for (int nb = 0; nb < 4; ++nb) {
            f32x4 t = {0.f, 0.f, 0.f, 0.f};
            t = MFMA(a[sub][0], b[0][nb], t);
            t = MFMA(a[sub][1], b[1][nb], t);
            acc[sub][nb] = t;
        }

    const size_t nh = (size_t)n * NHEADS + h;
    if (z < 2) {
        const float sc = (z == 0) ? 0.18033688011112042f : 1.0f; // log2(e)/8
        unsigned short* o = (z == 0 ? q_ws : k_ws) + nh * SEQ * HD;
#pragma unroll
        for (int sub = 0; sub < 2; ++sub)
#pragma unroll
            for (int nb = 0; nb < 4; ++nb)
#pragma unroll
                for (int i = 0; i < 4; ++i)
                    o[(size_t)(s_base + 16 * sub + hi * 4 + i) * HD + lo + 16 * nb] =
                        f2bf(acc[sub][nb][i] * sc);
    } else {
        unsigned short* o = vt_ws + nh * HD * SEQ;
#pragma unroll
        for (int sub = 0; sub < 2; ++sub)
#pragma unroll
            for (int nb = 0; nb < 4; ++nb) {
                ushort4_t pk;
                pk[0] = f2bf(acc[sub][nb][0]); pk[1] = f2bf(acc[sub][nb][1]);
                pk[2] = f2bf(acc[sub][nb][2]); pk[3] = f2bf(acc[sub][nb][3]);
                *(ushort4_t*)(o + (size_t)(lo + 16 * nb) * SEQ + s_base + 16 * sub + hi * 4) = pk;
            }
    }
}

// ---------------------------------------------------------------------------
// Kernel 2: Wo fp32 -> bf16 (unchanged)
// ---------------------------------------------------------------------------
__global__ __launch_bounds__(256) void wconv_kernel(
    const float* __restrict__ Wo, unsigned short* __restrict__ wob)
{
    const int idx = (blockIdx.x * 256 + threadIdx.x) * 8;
    const float4* p = (const float4*)(Wo + idx);
    short8 r = f8_to_bf8(p[0], p[1]);
    *(short8*)(wob + idx) = r;
}

// ---------------------------------------------------------------------------
// Kernel 2a: Wq/Wk/Wv fp32 -> bf16, packed [z][64][64]. 6 blocks x 2048 elems.
// ---------------------------------------------------------------------------
__global__ __launch_bounds__(256) void wqkvconv_kernel(
    const float* __restrict__ Wq, const float* __restrict__ Wk,
    const float* __restrict__ Wv, unsigned short* __restrict__ wqkvb)
{
    const int idx = (blockIdx.x * 256 + threadIdx.x) * 8;   // 0..12280
    const float* src = (idx < 4096) ? (Wq + idx)
                     : (idx < 8192) ? (Wk + idx - 4096)
                                    : (Wv + idx - 8192);
    const float4* p = (const float4*)src;
    short8 r = f8_to_bf8(p[0], p[1]);
    *(short8*)(wqkvb + idx) = r;
}

// ---------------------------------------------------------------------------
// Kernel 2b: per-(n, 64-key-tile) mask-zero flags (unchanged)
// ---------------------------------------------------------------------------
__global__ __launch_bounds__(64) void maskflags_kernel(
    const int* __restrict__ mask, unsigned* __restrict__ flags)
{
    const int n = blockIdx.x;
    const int t = threadIdx.x;           // 64 threads; 0..31 scan tiles
    bool has0 = false;
    if (t < 32) {
        const int* mrow = mask + (size_t)n * SEQ + t * 64;
#pragma unroll 4
        for (int j = 0; j < 64; j += 4) {
            int4 m4 = *(const int4*)(mrow + j);
            has0 |= (m4.x == 0) | (m4.y == 0) | (m4.z == 0) | (m4.w == 0);
        }
    }
    unsigned long long b = __ballot(has0);
    if (t == 0) flags[n] = (unsigned)(b & 0xffffffffu);
}

// ---------------------------------------------------------------------------
// Kernel 3: flash attention (byte-identical to round 12, passed at 57us).
// ---------------------------------------------------------------------------
__global__ __launch_bounds__(512, 2) void attn_kernel(
    const unsigned short* __restrict__ q_ws, const unsigned short* __restrict__ k_ws,
    const unsigned short* __restrict__ vt_ws, const int* __restrict__ mask,
    const unsigned* __restrict__ flags, unsigned short* __restrict__ ao_ws)
{
    __shared__ __align__(16) unsigned short klds[64][72];  // [key][d], padded
    __shared__ __align__(16) unsigned short vlds[64][72];  // [d][key], padded
    __shared__ __align__(16) int            mlds[64];
    __shared__ __align__(16) unsigned short plds[8][2][16][72];

    const int tid  = threadIdx.x;
    const int lane = tid & 63;
    const int w    = tid >> 6;                  // 0..7
    const int lo = lane & 15, hi = lane >> 4;
    const int bid = (blockIdx.x & 7) * 32 + (blockIdx.x >> 3);
    const int wid = bid * 8 + w;
    const int qt2 = wid & 63;          // 32-row q-block index (S/32 = 64)
    const int h   = (wid >> 6) & 7;
    const int n   = wid >> 9;
    const size_t nh = (size_t)n * NHEADS + h;

    const unsigned short* qp = q_ws + nh * SEQ * HD;
    const unsigned short* kp = k_ws + nh * SEQ * HD;
    const unsigned short* vp = vt_ws + nh * HD * SEQ;
    const int* mp = mask + (size_t)n * SEQ;
    const unsigned fl = flags[n];

    const int q0 = qt2 * 32;
    short8 aq[2][2];
#pragma unroll
    for (int qi = 0; qi < 2; ++qi)
#pragma unroll
        for (int kb = 0; kb < 2; ++kb)
            aq[qi][kb] = *(const short8*)(qp + (size_t)(q0 + 16 * qi + lo) * HD
                                          + kb * 32 + hi * 8);

    f32x4 o[2][4];
    float lacc[2] = {0.f, 0.f};
#pragma unroll
    for (int qi = 0; qi < 2; ++qi)
#pragma unroll
        for (int nb = 0; nb < 4; ++nb)
            o[qi][nb] = (f32x4){0.f, 0.f, 0.f, 0.f};

    const int sr = tid >> 3;                  // staged row 0..63
    const int sc = (tid & 7) * 8;             // staged col (shorts)

    short8 rk = *(const short8*)(kp + (size_t)sr * HD + sc);
    short8 rv = *(const short8*)(vp + (size_t)sr * SEQ + sc);
    int    rm = (w == 0) ? mp[lane] : 0;

    for (int t = 0; t < 32; ++t) {
        const int kt = t * 64;
        __syncthreads();                      // (A) done reading tile t-1
        *(short8*)(&klds[sr][sc]) = rk;
        *(short8*)(&vlds[sr][sc]) = rv;
        if (w == 0) mlds[lane] = rm;
        __syncthreads();                      // (B) tile t visible

        if (t < 31) {                         // prefetch tile t+1
            const int ktn = kt + 64;
            rk = *(const short8*)(kp + (size_t)(ktn + sr) * HD + sc);
            rv = *(const short8*)(vp + (size_t)sr * SEQ + ktn + sc);
            rm = (w == 0) ? mp[ktn + lane] : 0;
        }

        short8 k0[4], k1[4], va0[4], va1[4];
#pragma unroll
        for (int nb = 0; nb < 4; ++nb) {
            k0[nb]  = *(const short8*)(&klds[16 * nb + lo][hi * 8]);
            k1[nb]  = *(const short8*)(&klds[16 * nb + lo][32 + hi * 8]);
            va0[nb] = *(const short8*)(&vlds[16 * nb + lo][hi * 8]);
            va1[nb] = *(const short8*)(&vlds[16 * nb + lo][32 + hi * 8]);
        }
        const bool masked = (fl >> t) & 1u;
#pragma unroll
        for (int qi = 0; qi < 2; ++qi) {
            f32x4 e[4];
#pragma unroll
            for (int nb = 0; nb < 4; ++nb) {
                f32x4 tt = {0.f, 0.f, 0.f, 0.f};
                tt = MFMA(k0[nb], aq[qi][0], tt);
                tt = MFMA(k1[nb], aq[qi][1], tt);
                e[nb] = tt;
            }
            if (masked) {
#pragma unroll
                for (int nb = 0; nb < 4; ++nb) {
                    const int4 mm = *(const int4*)(&mlds[16 * nb + 4 * hi]);
                    if (mm.x == 0) e[nb][0] = -1e30f;
                    if (mm.y == 0) e[nb][1] = -1e30f;
                    if (mm.z == 0) e[nb][2] = -1e30f;
                    if (mm.w == 0) e[nb][3] = -1e30f;
                }
            }
#pragma unroll
            for (int nb = 0; nb < 4; ++nb) {
                float p0 = __builtin_amdgcn_exp2f(e[nb][0]);
                float p1 = __builtin_amdgcn_exp2f(e[nb][1]);
                float p2 = __builtin_amdgcn_exp2f(e[nb][2]);
                float p3 = __builtin_amdgcn_exp2f(e[nb][3]);
                lacc[qi] += (p0 + p1) + (p2 + p3);
                uint2 pk;
                pk.x = cvt_pk_bf16(p0, p1);
                pk.y = cvt_pk_bf16(p2, p3);
                *(uint2*)(&plds[w][qi][lo][16 * nb + 4 * hi]) = pk;
            }
            short8 pa0 = *(const short8*)(&plds[w][qi][lo][hi * 8]);
            short8 pa1 = *(const short8*)(&plds[w][qi][lo][32 + hi * 8]);
#pragma unroll
            for (int nb = 0; nb < 4; ++nb) {
                o[qi][nb] = MFMA(va0[nb], pa0, o[qi][nb]);
                o[qi][nb] = MFMA(va1[nb], pa1, o[qi][nb]);
            }
        }
    }

#pragma unroll
    for (int qi = 0; qi < 2; ++qi) {
        lacc[qi] += __shfl_xor(lacc[qi], 16);
        lacc[qi] += __shfl_xor(lacc[qi], 32);
        const float linv = 1.0f / lacc[qi];
        unsigned short* op = ao_ws + ((size_t)n * SEQ + q0 + 16 * qi + lo) * EMB + h * HD;
#pragma unroll
        for (int nb = 0; nb < 4; ++nb) {
            ushort4_t pk;
            pk[0] = f2bf(o[qi][nb][0] * linv);
            pk[1] = f2bf(o[qi][nb][1] * linv);
            pk[2] = f2bf(o[qi][nb][2] * linv);
            pk[3] = f2bf(o[qi][nb][3] * linv);
            *(ushort4_t*)(op + 16 * nb + 4 * hi) = pk;
        }
    }
}

// ---------------------------------------------------------------------------
// Kernel 4: output projection, v2. 2 m-subtiles per wave: B loads shared by
// both A rows (6 loads per 8 MFMAs). grid = 64 mt x 8 nc = 512 blocks.
// ---------------------------------------------------------------------------
__global__ __launch_bounds__(256) void out_proj_kernel(
    const unsigned short* __restrict__ ao_ws, const unsigned short* __restrict__ wob,
    const float* __restrict__ bo, float* __restrict__ out)
{
    const int bid = blockIdx.x;
    const int nc = bid & 7;
    const int mt = bid >> 3;            // 0..63, block covers 128 rows
    const int lane = threadIdx.x & 63;
    const int w = threadIdx.x >> 6;
    const int lo = lane & 15, hi = lane >> 4;
    const int m0 = mt * 128 + w * 32;   // wave covers 32 rows
    const int e0 = nc * 64;

    f32x4 acc[2][4];
#pragma unroll
    for (int sub = 0; sub < 2; ++sub)
#pragma unroll
        for (int nb = 0; nb < 4; ++nb)
            acc[sub][nb] = (f32x4){0.f, 0.f, 0.f, 0.f};

    const unsigned short* ar0 = ao_ws + (size_t)(m0 + lo) * EMB;
    const unsigned short* ar1 = ao_ws + (size_t)(m0 + 16 + lo) * EMB;
    for (int k0 = 0; k0 < EMB; k0 += 32) {
        short8 a0 = *(const short8*)(ar0 + k0 + hi * 8);
        short8 a1 = *(const short8*)(ar1 + k0 + hi * 8);
#pragma unroll
        for (int nb = 0; nb < 4; ++nb) {
            short8 b = *(const short8*)(wob + (size_t)(e0 + lo + 16 * nb) * EMB + k0 + hi * 8);
            acc[0][nb] = MFMA(a0, b, acc[0][nb]);
            acc[1][nb] = MFMA(a1, b, acc[1][nb]);
        }
    }
#pragma unroll
    for (int sub = 0; sub < 2; ++sub)
#pragma unroll
        for (int nb = 0; nb < 4; ++nb) {
            float bias = bo[e0 + lo + 16 * nb];
#pragma unroll
            for (int i = 0; i < 4; ++i)
                out[(size_t)(m0 + 16 * sub + hi * 4 + i) * EMB + e0 + lo + 16 * nb] =
                    acc[sub][nb][i] + bias;
        }
}

// ---------------------------------------------------------------------------
extern "C" void kernel_launch(void* const* d_in, const int* in_sizes, int n_in,
                              void* d_out, int out_size, void* d_ws, size_t ws_size,
                              hipStream_t stream)
{
    const float* vin = (const float*)d_in[0];
    const float* kin = (const float*)d_in[1];
    const float* qin = (const float*)d_in[2];
    const int*  mask = (const int*)d_in[3];
    const float* Wv  = (const float*)d_in[4];
    const float* Wk  = (const float*)d_in[5];
    const float* Wq  = (const float*)d_in[6];
    const float* Wo  = (const float*)d_in[7];
    const float* bo  = (const float*)d_in[8];
    float* out = (float*)d_out;

    const int N = in_sizes[0] / (SEQ * EMB);   // 4

    char* ws = (char*)d_ws;
    const size_t qkv_bytes = (size_t)N * NHEADS * SEQ * HD * 2;  // 8.39 MB each
    unsigned short* q_ws  = (unsigned short*)(ws);
    unsigned short* k_ws  = (unsigned short*)(ws + qkv_bytes);
    unsigned short* vt_ws = (unsigned short*)(ws + 2 * qkv_bytes);
    unsigned short* ao_ws = (unsigned short*)(ws + 3 * qkv_bytes);
    unsigned short* wob   = (unsigned short*)(ws + 4 * qkv_bytes);
    unsigned*       flags = (unsigned*)(ws + 4 * qkv_bytes + (size_t)EMB * EMB * 2);
    unsigned short* wqkvb = (unsigned short*)(ws + 4 * qkv_bytes + (size_t)EMB * EMB * 2 + 4096);

    hipLaunchKernelGGL(wconv_kernel, dim3(EMB * EMB / 2048), dim3(256), 0, stream,
                       Wo, wob);
    hipLaunchKernelGGL(wqkvconv_kernel, dim3(6), dim3(256), 0, stream,
                       Wq, Wk, Wv, wqkvb);
    hipLaunchKernelGGL(maskflags_kernel, dim3(N), dim3(64), 0, stream,
                       mask, flags);
    hipLaunchKernelGGL(qkv_proj_kernel, dim3(N * NHEADS * (SEQ / 128), 3), dim3(256), 0, stream,
                       vin, kin, qin, wqkvb, q_ws, k_ws, vt_ws);
    hipLaunchKernelGGL(attn_kernel, dim3(N * NHEADS * (SEQ / 32) / 8), dim3(512), 0, stream,
                       q_ws, k_ws, vt_ws, mask, flags, ao_ws);
    hipLaunchKernelGGL(out_proj_kernel, dim3((N * SEQ / 128) * (EMB / 64)), dim3(256), 0, stream,
                       ao_ws, wob, bo, out);
}

// Round 14
// 95.611 us; speedup vs baseline: 9.1753x; 1.1318x over previous
//
#include <hip/hip_runtime.h>
#include <hip/hip_bf16.h>

#define EMB 512
#define NHEADS 8
#define HD 64
#define SEQ 2048

typedef float f32x4 __attribute__((ext_vector_type(4)));
typedef float f32x16 __attribute__((ext_vector_type(16)));
typedef short short8 __attribute__((ext_vector_type(8)));
typedef unsigned short ushort4_t __attribute__((ext_vector_type(4)));
typedef unsigned uint2v __attribute__((ext_vector_type(2)));

#define MFMA(a, b, c)   __builtin_amdgcn_mfma_f32_16x16x32_bf16((a), (b), (c), 0, 0, 0)
#define MFMA32(a, b, c) __builtin_amdgcn_mfma_f32_32x32x16_bf16((a), (b), (c), 0, 0, 0)

__device__ inline unsigned short f2bf(float f) {
    union { float f; unsigned u; } v; v.f = f;
    unsigned r = v.u + 0x7fffu + ((v.u >> 16) & 1u);   // round-to-nearest-even
    return (unsigned short)(r >> 16);
}

__device__ inline unsigned cvt_pk_bf16(float a, float b) {
    unsigned r;
    asm("v_cvt_pk_bf16_f32 %0, %1, %2" : "=v"(r) : "v"(a), "v"(b));
    return r;  // low16 = bf16(a), high16 = bf16(b)
}

// v_permlane32_swap_b32: a[32:63] <-> b[0:31] (in place, both updated)
__device__ inline void plswap(unsigned &a, unsigned &b) {
#if __has_builtin(__builtin_amdgcn_permlane32_swap)
    uint2v r = __builtin_amdgcn_permlane32_swap(a, b, false, false);
    a = r[0]; b = r[1];
#else
    asm volatile("v_permlane32_swap_b32 %0, %1" : "+v"(a), "+v"(b));
#endif
}

__device__ inline short8 mk8(unsigned a, unsigned b, unsigned c, unsigned d) {
    union { unsigned u[4]; short8 s; } x;
    x.u[0] = a; x.u[1] = b; x.u[2] = c; x.u[3] = d;
    return x.s;
}

__device__ inline short8 f8_to_bf8(float4 a, float4 b) {
    short8 r;
    r[0] = (short)f2bf(a.x); r[1] = (short)f2bf(a.y);
    r[2] = (short)f2bf(a.z); r[3] = (short)f2bf(a.w);
    r[4] = (short)f2bf(b.x); r[5] = (short)f2bf(b.y);
    r[6] = (short)f2bf(b.z); r[7] = (short)f2bf(b.w);
    return r;
}

// ---------------------------------------------------------------------------
// Kernel 1: per-head QKV projection (unchanged from round 13, verified)
// ---------------------------------------------------------------------------
__global__ __launch_bounds__(256) void qkv_proj_kernel(
    const float* __restrict__ vin, const float* __restrict__ kin,
    const float* __restrict__ qin, const unsigned short* __restrict__ wqkvb,
    unsigned short* __restrict__ q_ws, unsigned short* __restrict__ k_ws,
    unsigned short* __restrict__ vt_ws)
{
    const int z = blockIdx.y;
    const float* __restrict__ x = (z == 0) ? qin : (z == 1 ? kin : vin);
    const unsigned short* __restrict__ wb = wqkvb + z * HD * HD;

    const int bid = blockIdx.x;
    const int st = bid & 15;
    const int h  = (bid >> 4) & 7;
    const int n  = bid >> 7;

    const int lane = threadIdx.x & 63;
    const int w    = threadIdx.x >> 6;
    const int lo = lane & 15, hi = lane >> 4;
    const int s_base = st * 128 + w * 32;

    short8 b[2][4];
#pragma unroll
    for (int nb = 0; nb < 4; ++nb)
#pragma unroll
        for (int kb = 0; kb < 2; ++kb)
            b[kb][nb] = *(const short8*)(wb + (lo + 16 * nb) * HD + kb * 32 + hi * 8);

    short8 a[2][2];
#pragma unroll
    for (int sub = 0; sub < 2; ++sub) {
        const float* xr = x + ((size_t)n * SEQ + s_base + 16 * sub + lo) * EMB + h * HD;
#pragma unroll
        for (int kb = 0; kb < 2; ++kb) {
            const float4* p = (const float4*)(xr + kb * 32 + hi * 8);
            a[sub][kb] = f8_to_bf8(p[0], p[1]);
        }
    }

    f32x4 acc[2][4];
#pragma unroll
    for (int sub = 0; sub < 2; ++sub)
#pragma unroll
        for (int nb = 0; nb < 4; ++nb) {
            f32x4 t = {0.f, 0.f, 0.f, 0.f};
            t = MFMA(a[sub][0], b[0][nb], t);
            t = MFMA(a[sub][1], b[1][nb], t);
            acc[sub][nb] = t;
        }

    const size_t nh = (size_t)n * NHEADS + h;
    if (z < 2) {
        const float sc = (z == 0) ? 0.18033688011112042f : 1.0f; // log2(e)/8
        unsigned short* o = (z == 0 ? q_ws : k_ws) + nh * SEQ * HD;
#pragma unroll
        for (int sub = 0; sub < 2; ++sub)
#pragma unroll
            for (int nb = 0; nb < 4; ++nb)
#pragma unroll
                for (int i = 0; i < 4; ++i)
                    o[(size_t)(s_base + 16 * sub + hi * 4 + i) * HD + lo + 16 * nb] =
                        f2bf(acc[sub][nb][i] * sc);
    } else {
        unsigned short* o = vt_ws + nh * HD * SEQ;
#pragma unroll
        for (int sub = 0; sub < 2; ++sub)
#pragma unroll
            for (int nb = 0; nb < 4; ++nb) {
                ushort4_t pk;
                pk[0] = f2bf(acc[sub][nb][0]); pk[1] = f2bf(acc[sub][nb][1]);
                pk[2] = f2bf(acc[sub][nb][2]); pk[3] = f2bf(acc[sub][nb][3]);
                *(ushort4_t*)(o + (size_t)(lo + 16 * nb) * SEQ + s_base + 16 * sub + hi * 4) = pk;
            }
    }
}

// ---------------------------------------------------------------------------
// Kernel 2: Wo fp32 -> bf16 (unchanged)
// ---------------------------------------------------------------------------
__global__ __launch_bounds__(256) void wconv_kernel(
    const float* __restrict__ Wo, unsigned short* __restrict__ wob)
{
    const int idx = (blockIdx.x * 256 + threadIdx.x) * 8;
    const float4* p = (const float4*)(Wo + idx);
    short8 r = f8_to_bf8(p[0], p[1]);
    *(short8*)(wob + idx) = r;
}

// ---------------------------------------------------------------------------
// Kernel 2a: Wq/Wk/Wv fp32 -> bf16, packed [z][64][64] (unchanged)
// ---------------------------------------------------------------------------
__global__ __launch_bounds__(256) void wqkvconv_kernel(
    const float* __restrict__ Wq, const float* __restrict__ Wk,
    const float* __restrict__ Wv, unsigned short* __restrict__ wqkvb)
{
    const int idx = (blockIdx.x * 256 + threadIdx.x) * 8;
    const float* src = (idx < 4096) ? (Wq + idx)
                     : (idx < 8192) ? (Wk + idx - 4096)
                                    : (Wv + idx - 8192);
    const float4* p = (const float4*)src;
    short8 r = f8_to_bf8(p[0], p[1]);
    *(short8*)(wqkvb + idx) = r;
}

// ---------------------------------------------------------------------------
// Kernel 2b: per-(n, 64-key-tile) mask-zero flags (unchanged)
// ---------------------------------------------------------------------------
__global__ __launch_bounds__(64) void maskflags_kernel(
    const int* __restrict__ mask, unsigned* __restrict__ flags)
{
    const int n = blockIdx.x;
    const int t = threadIdx.x;
    bool has0 = false;
    if (t < 32) {
        const int* mrow = mask + (size_t)n * SEQ + t * 64;
#pragma unroll 4
        for (int j = 0; j < 64; j += 4) {
            int4 m4 = *(const int4*)(mrow + j);
            has0 |= (m4.x == 0) | (m4.y == 0) | (m4.z == 0) | (m4.w == 0);
        }
    }
    unsigned long long b = __ballot(has0);
    if (t == 0) flags[n] = (unsigned)(b & 0xffffffffu);
}

// ---------------------------------------------------------------------------
// Kernel 3: flash attention v3 — 32x32x16 MFMA, P fully in-register.
// Staging/barriers/grid identical to the verified round-12 structure.
// Per wave: 32 q-rows. QK^T swapped: D[key][q] (col=lane&31=q,
// row=(reg&3)+8(reg>>2)+4(lane>>5)=key). After cvt_pk, 4 permlane32_swaps
// per key-block convert the score words IN PLACE into the PV A-fragment
// (lane holds P[q=lane&31][16 keys]) — no LDS round-trip for P.
// PV = mfma(P, V^T-frags); l-sum = one shfl_xor(32).
// ---------------------------------------------------------------------------
__global__ __launch_bounds__(512, 1) void attn_kernel(
    const unsigned short* __restrict__ q_ws, const unsigned short* __restrict__ k_ws,
    const unsigned short* __restrict__ vt_ws, const int* __restrict__ mask,
    const unsigned* __restrict__ flags, unsigned short* __restrict__ ao_ws)
{
    __shared__ __align__(16) unsigned short klds[64][72];  // [key][d], padded
    __shared__ __align__(16) unsigned short vlds[64][72];  // [d][key], padded
    __shared__ __align__(16) int            mlds[64];
    __shared__ __align__(16) float          llds[8][32];

    const int tid  = threadIdx.x;
    const int lane = tid & 63;
    const int w    = tid >> 6;                  // 0..7
    const int l31  = lane & 31;
    const int hi5  = lane >> 5;                 // 0..1
    // XCD swizzle, grid=256 (bijective): 32 blocks/XCD
    const int bid = (blockIdx.x & 7) * 32 + (blockIdx.x >> 3);
    const int wid = bid * 8 + w;
    const int qb  = wid & 63;          // 32-row q-block (S/32 = 64)
    const int h   = (wid >> 6) & 7;
    const int n   = wid >> 9;
    const size_t nh = (size_t)n * NHEADS + h;

    const unsigned short* qp = q_ws + nh * SEQ * HD;
    const unsigned short* kp = k_ws + nh * SEQ * HD;
    const unsigned short* vp = vt_ws + nh * HD * SEQ;
    const int* mp = mask + (size_t)n * SEQ;
    const unsigned fl = flags[n];

    const int q0 = qb * 32;
    // Q as B-fragments: bq[s] = Q[q0 + l31][16s + 8*hi5 .. +7]
    short8 bq[4];
#pragma unroll
    for (int s = 0; s < 4; ++s)
        bq[s] = *(const short8*)(qp + (size_t)(q0 + l31) * HD + 16 * s + 8 * hi5);

    f32x16 o0, o1;
#pragma unroll
    for (int r = 0; r < 16; ++r) { o0[r] = 0.f; o1[r] = 0.f; }
    float lacc = 0.f;

    // staging (identical to round 12): 512 threads cover 64 rows x 8 chunks
    const int sr = tid >> 3;
    const int sc = (tid & 7) * 8;
    short8 rk = *(const short8*)(kp + (size_t)sr * HD + sc);
    short8 rv = *(const short8*)(vp + (size_t)sr * SEQ + sc);
    int    rm = (w == 0) ? mp[lane] : 0;

    for (int t = 0; t < 32; ++t) {
        const int kt = t * 64;
        __syncthreads();                      // (A) done reading tile t-1
        *(short8*)(&klds[sr][sc]) = rk;
        *(short8*)(&vlds[sr][sc]) = rv;
        if (w == 0) mlds[lane] = rm;
        __syncthreads();                      // (B) tile t visible

        if (t < 31) {                         // prefetch tile t+1
            const int ktn = kt + 64;
            rk = *(const short8*)(kp + (size_t)(ktn + sr) * HD + sc);
            rv = *(const short8*)(vp + (size_t)sr * SEQ + ktn + sc);
            rm = (w == 0) ? mp[ktn + lane] : 0;
        }

        const bool masked = (fl >> t) & 1u;
        short8 pa[4];                         // PV A-fragments (keys 0..63)
#pragma unroll
        for (int kb = 0; kb < 2; ++kb) {
            // S^T = K Q^T : D[key = 32kb + row][q = l31]
            f32x16 e;
#pragma unroll
            for (int r = 0; r < 16; ++r) e[r] = 0.f;
#pragma unroll
            for (int s = 0; s < 4; ++s) {
                short8 ak = *(const short8*)(&klds[32 * kb + l31][16 * s + 8 * hi5]);
                e = MFMA32(ak, bq[s], e);
            }
            if (masked) {
#pragma unroll
                for (int r = 0; r < 16; ++r) {
                    const int key = 32 * kb + (r & 3) + 8 * (r >> 2) + 4 * hi5;
                    if (mlds[key] == 0) e[r] = -1e30f;
                }
            }
            // no-max softmax + pack: wv[r2] = bf16x2 of key pair
            unsigned wv[8];
#pragma unroll
            for (int r2 = 0; r2 < 8; ++r2) {
                float p0 = __builtin_amdgcn_exp2f(e[2 * r2]);
                float p1 = __builtin_amdgcn_exp2f(e[2 * r2 + 1]);
                lacc += p0 + p1;
                wv[r2] = cvt_pk_bf16(p0, p1);
            }
            // in-place half-swap -> words land in PV A-fragment order
            plswap(wv[0], wv[2]); plswap(wv[1], wv[3]);
            plswap(wv[4], wv[6]); plswap(wv[5], wv[7]);
            pa[2 * kb]     = mk8(wv[0], wv[1], wv[2], wv[3]);
            pa[2 * kb + 1] = mk8(wv[4], wv[5], wv[6], wv[7]);
        }
        // O += P V  (B-fragments from vlds; d-blocks 0 and 1)
#pragma unroll
        for (int s = 0; s < 4; ++s) {
            short8 bv0 = *(const short8*)(&vlds[l31][16 * s + 8 * hi5]);
            short8 bv1 = *(const short8*)(&vlds[32 + l31][16 * s + 8 * hi5]);
            o0 = MFMA32(pa[s], bv0, o0);
            o1 = MFMA32(pa[s], bv1, o1);
        }
    }

    // l: lane holds partial for q = l31 (its 16 key-rows); partner has rest
    lacc += __shfl_xor(lacc, 32);
    if (lane < 32) llds[w][lane] = 1.0f / lacc;   // same-wave, in-order

    unsigned short* op = ao_ws + ((size_t)n * SEQ + q0) * EMB + h * HD;
#pragma unroll
    for (int r = 0; r < 16; ++r) {
        const int qrow = (r & 3) + 8 * (r >> 2) + 4 * hi5;
        const float linv = llds[w][qrow];
        op[(size_t)qrow * EMB + l31]      = f2bf(o0[r] * linv);
        op[(size_t)qrow * EMB + 32 + l31] = f2bf(o1[r] * linv);
    }
}

// ---------------------------------------------------------------------------
// Kernel 4: output projection (unchanged from round 13, verified)
// ---------------------------------------------------------------------------
__global__ __launch_bounds__(256) void out_proj_kernel(
    const unsigned short* __restrict__ ao_ws, const unsigned short* __restrict__ wob,
    const float* __restrict__ bo, float* __restrict__ out)
{
    const int bid = blockIdx.x;
    const int nc = bid & 7;
    const int mt = bid >> 3;
    const int lane = threadIdx.x & 63;
    const int w = threadIdx.x >> 6;
    const int lo = lane & 15, hi = lane >> 4;
    const int m0 = mt * 128 + w * 32;
    const int e0 = nc * 64;

    f32x4 acc[2][4];
#pragma unroll
    for (int sub = 0; sub < 2; ++sub)
#pragma unroll
        for (int nb = 0; nb < 4; ++nb)
            acc[sub][nb] = (f32x4){0.f, 0.f, 0.f, 0.f};

    const unsigned short* ar0 = ao_ws + (size_t)(m0 + lo) * EMB;
    const unsigned short* ar1 = ao_ws + (size_t)(m0 + 16 + lo) * EMB;
    for (int k0 = 0; k0 < EMB; k0 += 32) {
        short8 a0 = *(const short8*)(ar0 + k0 + hi * 8);
        short8 a1 = *(const short8*)(ar1 + k0 + hi * 8);
#pragma unroll
        for (int nb = 0; nb < 4; ++nb) {
            short8 b = *(const short8*)(wob + (size_t)(e0 + lo + 16 * nb) * EMB + k0 + hi * 8);
            acc[0][nb] = MFMA(a0, b, acc[0][nb]);
            acc[1][nb] = MFMA(a1, b, acc[1][nb]);
        }
    }
#pragma unroll
    for (int sub = 0; sub < 2; ++sub)
#pragma unroll
        for (int nb = 0; nb < 4; ++nb) {
            float bias = bo[e0 + lo + 16 * nb];
#pragma unroll
            for (int i = 0; i < 4; ++i)
                out[(size_t)(m0 + 16 * sub + hi * 4 + i) * EMB + e0 + lo + 16 * nb] =
                    acc[sub][nb][i] + bias;
        }
}

// ---------------------------------------------------------------------------
extern "C" void kernel_launch(void* const* d_in, const int* in_sizes, int n_in,
                              void* d_out, int out_size, void* d_ws, size_t ws_size,
                              hipStream_t stream)
{
    const float* vin = (const float*)d_in[0];
    const float* kin = (const float*)d_in[1];
    const float* qin = (const float*)d_in[2];
    const int*  mask = (const int*)d_in[3];
    const float* Wv  = (const float*)d_in[4];
    const float* Wk  = (const float*)d_in[5];
    const float* Wq  = (const float*)d_in[6];
    const float* Wo  = (const float*)d_in[7];
    const float* bo  = (const float*)d_in[8];
    float* out = (float*)d_out;

    const int N = in_sizes[0] / (SEQ * EMB);   // 4

    char* ws = (char*)d_ws;
    const size_t qkv_bytes = (size_t)N * NHEADS * SEQ * HD * 2;  // 8.39 MB each
    unsigned short* q_ws  = (unsigned short*)(ws);
    unsigned short* k_ws  = (unsigned short*)(ws + qkv_bytes);
    unsigned short* vt_ws = (unsigned short*)(ws + 2 * qkv_bytes);
    unsigned short* ao_ws = (unsigned short*)(ws + 3 * qkv_bytes);
    unsigned short* wob   = (unsigned short*)(ws + 4 * qkv_bytes);
    unsigned*       flags = (unsigned*)(ws + 4 * qkv_bytes + (size_t)EMB * EMB * 2);
    unsigned short* wqkvb = (unsigned short*)(ws + 4 * qkv_bytes + (size_t)EMB * EMB * 2 + 4096);

    hipLaunchKernelGGL(wconv_kernel, dim3(EMB * EMB / 2048), dim3(256), 0, stream,
                       Wo, wob);
    hipLaunchKernelGGL(wqkvconv_kernel, dim3(6), dim3(256), 0, stream,
                       Wq, Wk, Wv, wqkvb);
    hipLaunchKernelGGL(maskflags_kernel, dim3(N), dim3(64), 0, stream,
                       mask, flags);
    hipLaunchKernelGGL(qkv_proj_kernel, dim3(N * NHEADS * (SEQ / 128), 3), dim3(256), 0, stream,
                       vin, kin, qin, wqkvb, q_ws, k_ws, vt_ws);
    hipLaunchKernelGGL(attn_kernel, dim3(N * NHEADS * (SEQ / 32) / 8), dim3(512), 0, stream,
                       q_ws, k_ws, vt_ws, mask, flags, ao_ws);
    hipLaunchKernelGGL(out_proj_kernel, dim3((N * SEQ / 128) * (EMB / 64)), dim3(256), 0, stream,
                       ao_ws, wob, bo, out);
}